// Round 2
// baseline (3920.190 us; speedup 1.0000x reference)
//
#include <hip/hip_runtime.h>

typedef unsigned short u16;
typedef __bf16 bf16x8 __attribute__((ext_vector_type(8)));
typedef float f32x4 __attribute__((ext_vector_type(4)));

union FragU { bf16x8 v; u16 u[8]; uint4 q; };
struct Pf { f32x4 a, b, c, d; };   // 16 f32 gate-U partials per thread

__device__ __forceinline__ float bf2f(u16 u) {
  union { unsigned int i; float f; } x; x.i = ((unsigned int)u) << 16; return x.f;
}
__device__ __forceinline__ u16 f2bf(float f) {
  union { float f; unsigned int i; } x; x.f = f;
  return (u16)((x.i + 0x7FFFu + ((x.i >> 16) & 1u)) >> 16);
}

#define ST 72        // padded row stride (bf16 elems): 144B rows, 16B aligned
#define FST 136      // featsT stride (128 + 8)
#define CH 16        // timesteps per chunk
// workspace layout (bytes):
//   [0, 524288)            h carry, bf16 [64][4096]
//   [524288, 9961472)      S2 padded tiles, u16 [1024 rec][64*72]  (9216 B each)
//   [9961472, 60293120)    gu f32 [1024 rec][768 tid][16]          (49152 B each)
#define WS_S2_OFF 524288
#define WS_GU_OFF 9961472
#define WS_NEED   60293120

// ============================================================================
// Kernel 1: time-parallel prepass. One block per (b,t): computes
//   xt = feats@encW+b, S2 = At@At, yx1 = At@xt, yx2 = S2@xt,
//   gu = xt@Wu0 + yx1@Wu1 + yx2@Wu2   (f32, per-tid packed -> ws)
//   S2 (bf16 padded tile image)       -> ws
// LDS 64.8 KB -> 2 blocks/CU naturally; no forced launch bound (spill risk).
// ============================================================================
__global__ __launch_bounds__(768) void cfgcn_pre(
    const void* __restrict__ frames, const void* __restrict__ adj,
    const void* __restrict__ encW, const void* __restrict__ encb,
    const void* __restrict__ Wfu, const void* __restrict__ Wgu, const void* __restrict__ Wcu,
    char* __restrict__ ws, int t0)
{
  __shared__ alignas(16) u16 lds[32256];
  u16* sh_Y1  = lds;            // 4608
  u16* sh_Y2  = lds + 4608;     // 4608   (Y1/Y2 overlap featsT: fT dead after phase B)
  u16* sh_fT  = lds;            // 64 x FST = 8704 (< 9216)
  u16* sh_At  = lds +  9216;
  u16* sh_AtT = lds + 13824;
  u16* sh_S2  = lds + 18432;
  u16* sh_xt  = lds + 23040;
  u16* sh_xtT = lds + 27648;
  __shared__ float sh_encB[64];
  __shared__ int sh_flag;

  const int bx  = blockIdx.x;          // rec index = b*CH + (t - t0)
  const int b   = bx >> 4;
  const int t   = t0 + (bx & 15);
  const int tid = threadIdx.x;
  const int w    = tid >> 6;
  const int lane = tid & 63;
  const int quad = lane >> 4;
  const int l15  = lane & 15;

  // ---- dtype detection ----
  if (tid == 0) sh_flag = 0;
  __syncthreads();
  {
    int c = 0;
    const u16* fu = (const u16*)frames;
    for (int i = tid; i < 8192; i += 768) {
      u16 u = fu[i];
      c += ((u & 0x7F80u) >= 0x6000u) ? 1 : 0;
    }
    if (c) atomicAdd(&sh_flag, c);
  }
  __syncthreads();
  const bool isf32 = (sh_flag > 16);

  auto ldbf = [&](const void* p, int i) -> u16 {
    return isf32 ? f2bf(((const float*)p)[i]) : ((const u16*)p)[i];
  };
  auto ldf = [&](const void* p, int i) -> float {
    return isf32 ? ((const float*)p)[i] : bf2f(((const u16*)p)[i]);
  };
  auto fetch8 = [&](const void* p, int id) -> FragU {
    FragU f;
    if (!isf32) {
      f.q = ((const uint4*)p)[id];
    } else {
      const float4* fp = (const float4*)p;
      float4 lo = fp[2 * id], hi = fp[2 * id + 1];
      f.u[0] = f2bf(lo.x); f.u[1] = f2bf(lo.y); f.u[2] = f2bf(lo.z); f.u[3] = f2bf(lo.w);
      f.u[4] = f2bf(hi.x); f.u[5] = f2bf(hi.y); f.u[6] = f2bf(hi.z); f.u[7] = f2bf(hi.w);
    }
    return f;
  };

  // ---- weight fragments: Wu cat rows 0..191 = {Wf/g/c}_u[k=0..2] ----
  const void* Wup[3] = {Wfu, Wgu, Wcu};
  const int gate = w >> 2;
  const int colg = ((w & 3) * 16) + l15;
  FragU wfrag[6];
#pragma unroll
  for (int kc = 0; kc < 6; ++kc) {
#pragma unroll
    for (int j = 0; j < 8; ++j) {
      int r = kc * 32 + quad * 8 + j;
      wfrag[kc].u[j] = ldbf(Wup[gate], (r >> 6) * 4096 + (r & 63) * 64 + colg);
    }
  }
  FragU efrag[4];
#pragma unroll
  for (int kc = 0; kc < 4; ++kc) {
#pragma unroll
    for (int j = 0; j < 8; ++j) {
      int c = kc * 32 + quad * 8 + j;
      efrag[kc].u[j] = ldbf(encW, c * 64 + ((w & 3) * 16 + l15));
    }
  }
  if (tid < 64) sh_encB[tid] = ldf(encb, tid);

  // ---- stage At + At^T + featsT ----
  {
    const void* ag = isf32 ? (const void*)((const float*)adj + (size_t)(b * 128 + t) * 4096)
                           : (const void*)((const u16*)adj + (size_t)(b * 128 + t) * 4096);
    const void* fg = isf32 ? (const void*)((const float*)frames + (size_t)(b * 128 + t) * 8192)
                           : (const void*)((const u16*)frames + (size_t)(b * 128 + t) * 8192);
    for (int id = tid; id < 1536; id += 768) {
      if (id < 512) {
        FragU f = fetch8(ag, id);
        int r = id >> 3, c8 = (id & 7) * 8;
        *(uint4*)(sh_At + r * ST + c8) = f.q;
#pragma unroll
        for (int j = 0; j < 8; ++j) sh_AtT[(c8 + j) * ST + r] = f.u[j];
      } else {
        int k = id - 512;
        FragU f = fetch8(fg, k);
        int c = k >> 3, n8 = (k & 7) * 8;
#pragma unroll
        for (int j = 0; j < 8; ++j) sh_fT[(n8 + j) * FST + c] = f.u[j];
      }
    }
  }
  __syncthreads();

  auto tile64 = [&](const u16* A, const u16* BT, u16* C, int mt, int nt) {
    f32x4 acc = {0.f, 0.f, 0.f, 0.f};
    bf16x8 a0 = *(const bf16x8*)(A  + (mt * 16 + l15) * ST + quad * 8);
    bf16x8 b0 = *(const bf16x8*)(BT + (nt * 16 + l15) * ST + quad * 8);
    acc = __builtin_amdgcn_mfma_f32_16x16x32_bf16(a0, b0, acc, 0, 0, 0);
    bf16x8 a1 = *(const bf16x8*)(A  + (mt * 16 + l15) * ST + 32 + quad * 8);
    bf16x8 b1 = *(const bf16x8*)(BT + (nt * 16 + l15) * ST + 32 + quad * 8);
    acc = __builtin_amdgcn_mfma_f32_16x16x32_bf16(a1, b1, acc, 0, 0, 0);
    int cb = (mt * 16 + quad * 4) * ST + nt * 16 + l15;
    C[cb]          = f2bf(acc[0]);
    C[cb + ST]     = f2bf(acc[1]);
    C[cb + 2 * ST] = f2bf(acc[2]);
    C[cb + 3 * ST] = f2bf(acc[3]);
  };
  auto encTile = [&](int mt, int dt) {
    f32x4 acc = {0.f, 0.f, 0.f, 0.f};
#pragma unroll
    for (int kc = 0; kc < 4; ++kc) {
      bf16x8 a = *(const bf16x8*)(sh_fT + (mt * 16 + l15) * FST + kc * 32 + quad * 8);
      acc = __builtin_amdgcn_mfma_f32_16x16x32_bf16(a, efrag[kc].v, acc, 0, 0, 0);
    }
    int d = dt * 16 + l15;
    float eb = sh_encB[d];
#pragma unroll
    for (int r = 0; r < 4; ++r) {
      int n = mt * 16 + quad * 4 + r;
      u16 hv = f2bf(acc[r] + eb);
      sh_xt[n * ST + d]  = hv;
      sh_xtT[d * ST + n] = hv;
    }
  };

  f32x4 gacc[4];
  auto gstep = [&](const u16* buf, int koff, const FragU& wf) {
#pragma unroll
    for (int mt = 0; mt < 4; ++mt) {
      bf16x8 a = *(const bf16x8*)(buf + (mt * 16 + l15) * ST + koff + quad * 8);
      gacc[mt] = __builtin_amdgcn_mfma_f32_16x16x32_bf16(a, wf.v, gacc[mt], 0, 0, 0);
    }
  };

  // ---- Phase B: encoder + S2 ----
  encTile(w >> 2, w & 3);
  if (w < 4) encTile(3, w);
  tile64(sh_At, sh_AtT, sh_S2, w >> 2, w & 3);
  if (w < 4) tile64(sh_At, sh_AtT, sh_S2, 3, w);
  __syncthreads();

  // ---- Phase C: yx1 = At@xt, yx2 = S2@xt ; dump S2 tile -> ws ----
#pragma unroll
  for (int i = 0; i < 3; ++i) {
    int id = w + 12 * i;
    if (id < 16)      tile64(sh_At, sh_xtT, sh_Y1, id >> 2, id & 3);
    else if (id < 32) tile64(sh_S2, sh_xtT, sh_Y2, (id - 16) >> 2, (id - 16) & 3);
  }
  {
    uint4* s2o = (uint4*)(ws + WS_S2_OFF + (size_t)bx * 9216);
    for (int id = tid; id < 576; id += 768) s2o[id] = ((const uint4*)sh_S2)[id];
  }
  __syncthreads();

  // ---- Phase D: gu = [xt,yx1,yx2] @ W_u  -> ws (f32, per-tid packed) ----
  {
    f32x4 z = {0.f, 0.f, 0.f, 0.f};
    gacc[0] = z; gacc[1] = z; gacc[2] = z; gacc[3] = z;
  }
  gstep(sh_xt, 0, wfrag[0]); gstep(sh_xt, 32, wfrag[1]);
  gstep(sh_Y1, 0, wfrag[2]); gstep(sh_Y1, 32, wfrag[3]);
  gstep(sh_Y2, 0, wfrag[4]); gstep(sh_Y2, 32, wfrag[5]);
  {
    float* gp = (float*)(ws + WS_GU_OFF + (size_t)bx * 49152) + tid * 16;
    *(f32x4*)(gp + 0)  = gacc[0];
    *(f32x4*)(gp + 4)  = gacc[1];
    *(f32x4*)(gp + 8)  = gacc[2];
    *(f32x4*)(gp + 12) = gacc[3];
  }
}

// ============================================================================
// Kernel 2: sequential recurrence over CH timesteps. Per step:
//   E: gacc <- gu(regs); gacc += h@Wh[k0]; yh1 = At@h; yh2 = S2@h
//   F: gacc += [yh1,yh2]@Wh[k1,k2]; preacts -> sh_G
//   G: h_new = sig(ff)*tanh(gg)+(1-sig)*tanh(cc); pooled
//   H: wave0 decoder || waves 1..11 stage next At/S2; all prefetch next gu
// ============================================================================
__global__ __launch_bounds__(768, 1) void cfgcn_seq(
    const void* __restrict__ frames, const void* __restrict__ adj, const void* __restrict__ hid0,
    const void* __restrict__ Wfh, const void* __restrict__ Wgh, const void* __restrict__ Wch,
    const void* __restrict__ bfp, const void* __restrict__ bgp, const void* __restrict__ bcp,
    const void* __restrict__ dW1, const void* __restrict__ db1,
    const void* __restrict__ dW2, const void* __restrict__ db2,
    const void* __restrict__ dW3, const void* __restrict__ db3,
    const void* __restrict__ osc, const void* __restrict__ obi,
    void* __restrict__ outv, char* __restrict__ ws, int t0)
{
  __shared__ alignas(16) u16 lds[50688];
  u16* sh_h   = lds;            // 4608
  u16* sh_hT  = lds + 4608;
  u16* sh_Y1  = lds + 9216;
  u16* sh_Y2  = lds + 13824;
  u16* sh_G   = lds + 18432;    // 3*4608
  u16* sh_buf = lds + 32256;    // 2 x (At 4608 + S2 4608)
  __shared__ float sh_biasG[192], sh_pooled[64], sh_z1[128], sh_z2[64];
  __shared__ int sh_flag;

  const int b    = blockIdx.x;
  const int tid  = threadIdx.x;
  const int w    = tid >> 6;
  const int lane = tid & 63;
  const int quad = lane >> 4;
  const int l15  = lane & 15;

  if (tid == 0) sh_flag = 0;
  __syncthreads();
  {
    int c = 0;
    const u16* fu = (const u16*)frames;
    for (int i = tid; i < 8192; i += 768) {
      u16 u = fu[i];
      c += ((u & 0x7F80u) >= 0x6000u) ? 1 : 0;
    }
    if (c) atomicAdd(&sh_flag, c);
  }
  __syncthreads();
  const bool isf32 = (sh_flag > 16);

  auto ldbf = [&](const void* p, int i) -> u16 {
    return isf32 ? f2bf(((const float*)p)[i]) : ((const u16*)p)[i];
  };
  auto ldf = [&](const void* p, int i) -> float {
    return isf32 ? ((const float*)p)[i] : bf2f(((const u16*)p)[i]);
  };
  auto fetch8 = [&](const void* p, int id) -> FragU {
    FragU f;
    if (!isf32) {
      f.q = ((const uint4*)p)[id];
    } else {
      const float4* fp = (const float4*)p;
      float4 lo = fp[2 * id], hi = fp[2 * id + 1];
      f.u[0] = f2bf(lo.x); f.u[1] = f2bf(lo.y); f.u[2] = f2bf(lo.z); f.u[3] = f2bf(lo.w);
      f.u[4] = f2bf(hi.x); f.u[5] = f2bf(hi.y); f.u[6] = f2bf(hi.z); f.u[7] = f2bf(hi.w);
    }
    return f;
  };
  auto stout = [&](int i, float v) {
    if (isf32) ((float*)outv)[i] = v; else ((u16*)outv)[i] = f2bf(v);
  };

  // ---- W_h fragments (rows 0..191 = {Wf/g/c}_h[k=0..2]) ----
  const void* Whp[3] = {Wfh, Wgh, Wch};
  const int gate = w >> 2;
  const int colg = ((w & 3) * 16) + l15;
  FragU wfrag[6];
#pragma unroll
  for (int kc = 0; kc < 6; ++kc) {
#pragma unroll
    for (int j = 0; j < 8; ++j) {
      int r = kc * 32 + quad * 8 + j;
      wfrag[kc].u[j] = ldbf(Whp[gate], (r >> 6) * 4096 + (r & 63) * 64 + colg);
    }
  }
  if (tid < 192) {
    const void* bp = (tid < 64) ? bfp : (tid < 128 ? bgp : bcp);
    sh_biasG[tid] = ldf(bp, tid & 63);
  }

  u16* wsh = (u16*)ws;   // h carry (bf16)

  // ---- stage h (chunk 0: hid0 input; else: carried state) ----
  for (int st = tid; st < 512; st += 768) {
    FragU f;
    if (t0 == 0) {
      const void* hg = isf32 ? (const void*)((const float*)hid0 + (size_t)b * 4096)
                             : (const void*)((const u16*)hid0 + (size_t)b * 4096);
      f = fetch8(hg, st);
    } else {
      f.q = ((const uint4*)(wsh + (size_t)b * 4096))[st];
    }
    int n = st >> 3, d8 = (st & 7) * 8;
    *(uint4*)(sh_h + n * ST + d8) = f.q;
#pragma unroll
    for (int j = 0; j < 8; ++j) sh_hT[(d8 + j) * ST + n] = f.u[j];
  }

  auto tile64 = [&](const u16* A, const u16* BT, u16* C, int mt, int nt) {
    f32x4 acc = {0.f, 0.f, 0.f, 0.f};
    bf16x8 a0 = *(const bf16x8*)(A  + (mt * 16 + l15) * ST + quad * 8);
    bf16x8 b0 = *(const bf16x8*)(BT + (nt * 16 + l15) * ST + quad * 8);
    acc = __builtin_amdgcn_mfma_f32_16x16x32_bf16(a0, b0, acc, 0, 0, 0);
    bf16x8 a1 = *(const bf16x8*)(A  + (mt * 16 + l15) * ST + 32 + quad * 8);
    bf16x8 b1 = *(const bf16x8*)(BT + (nt * 16 + l15) * ST + 32 + quad * 8);
    acc = __builtin_amdgcn_mfma_f32_16x16x32_bf16(a1, b1, acc, 0, 0, 0);
    int cb = (mt * 16 + quad * 4) * ST + nt * 16 + l15;
    C[cb]          = f2bf(acc[0]);
    C[cb + ST]     = f2bf(acc[1]);
    C[cb + 2 * ST] = f2bf(acc[2]);
    C[cb + 3 * ST] = f2bf(acc[3]);
  };

  f32x4 gacc[4];
  auto gstep = [&](const u16* buf, int koff, const FragU& wf) {
#pragma unroll
    for (int mt = 0; mt < 4; ++mt) {
      bf16x8 a = *(const bf16x8*)(buf + (mt * 16 + l15) * ST + koff + quad * 8);
      gacc[mt] = __builtin_amdgcn_mfma_f32_16x16x32_bf16(a, wf.v, gacc[mt], 0, 0, 0);
    }
  };

  // stage At (from adj, dtype-converted) + S2 (tile image from ws) for step tln
  auto stageSeq = [&](int tn, int tln, int st0, int stride) {
    u16* dAt = sh_buf + (tln & 1) * 9216;
    u16* dS2 = dAt + 4608;
    const void* ag = isf32 ? (const void*)((const float*)adj + (size_t)(b * 128 + tn) * 4096)
                           : (const void*)((const u16*)adj + (size_t)(b * 128 + tn) * 4096);
    const uint4* s2g = (const uint4*)(ws + WS_S2_OFF + (size_t)((b << 4) + tln) * 9216);
    for (int id = st0; id < 1088; id += stride) {
      if (id < 512) {
        FragU f = fetch8(ag, id);
        int r = id >> 3, c8 = (id & 7) * 8;
        *(uint4*)(dAt + r * ST + c8) = f.q;
      } else {
        ((uint4*)dS2)[id - 512] = s2g[id - 512];
      }
    }
  };

  const float* gub = (const float*)(ws + WS_GU_OFF);
  Pf pA, pB;
  stageSeq(t0, 0, tid, 768);
  {
    const float* gp = gub + (size_t)(b << 4) * 12288 + tid * 16;
    pA.a = *(const f32x4*)(gp);     pA.b = *(const f32x4*)(gp + 4);
    pA.c = *(const f32x4*)(gp + 8); pA.d = *(const f32x4*)(gp + 12);
  }
  __syncthreads();

  auto step = [&](int t, int tl, Pf& use, Pf& nxt) {
    u16* At  = sh_buf + (tl & 1) * 9216;
    u16* S2v = At + 4608;

    // ---- Phase E: seed gacc from gu; h-part of gate; yh1/yh2 ----
    gacc[0] = use.a; gacc[1] = use.b; gacc[2] = use.c; gacc[3] = use.d;
    gstep(sh_h, 0, wfrag[0]); gstep(sh_h, 32, wfrag[1]);
#pragma unroll
    for (int i = 0; i < 3; ++i) {
      int id = w + 12 * i;
      if (id < 16)      tile64(At,  sh_hT, sh_Y1, id >> 2, id & 3);
      else if (id < 32) tile64(S2v, sh_hT, sh_Y2, (id - 16) >> 2, (id - 16) & 3);
    }
    __syncthreads();

    // ---- Phase F: gate += [yh1,yh2]@W_h ; preacts (+bias) -> sh_G ----
    gstep(sh_Y1, 0, wfrag[2]); gstep(sh_Y1, 32, wfrag[3]);
    gstep(sh_Y2, 0, wfrag[4]); gstep(sh_Y2, 32, wfrag[5]);
    {
      float bias = sh_biasG[w * 16 + l15];
      u16* G = sh_G + gate * 4608;
      int col = (w & 3) * 16 + l15;
#pragma unroll
      for (int mt = 0; mt < 4; ++mt) {
#pragma unroll
        for (int r = 0; r < 4; ++r)
          G[(mt * 16 + quad * 4 + r) * ST + col] = f2bf(gacc[mt][r] + bias);
      }
    }
    if (tid < 64) sh_pooled[tid] = 0.f;
    __syncthreads();

    // ---- Phase G: h_new + pooled ----
    {
      float psum = 0.f;
      int d = tid & 63;
#pragma unroll
      for (int i = 0; i < 6; ++i) {
        int idx = tid + i * 768;
        if (idx < 4096) {
          int n = idx >> 6;
          float ff = bf2f(sh_G[n * ST + d]);
          float gg = bf2f(sh_G[4608 + n * ST + d]);
          float cc = bf2f(sh_G[9216 + n * ST + d]);
          float sig = 1.f / (1.f + __expf(-ff));
          float tg = 1.f - 2.f / (__expf(2.f * gg) + 1.f);
          float tc = 1.f - 2.f / (__expf(2.f * cc) + 1.f);
          float hn = sig * tg + (1.f - sig) * tc;
          u16 hv = f2bf(hn);
          sh_h[n * ST + d]  = hv;
          sh_hT[d * ST + n] = hv;
          psum += hn;
          if (t == 127) stout(49152 + (b << 12) + idx, hn);     // final_hidden
          if (tl == 15) wsh[(size_t)b * 4096 + idx] = hv;       // h carry
        }
      }
      atomicAdd(&sh_pooled[d], psum);
    }
    __syncthreads();

    // ---- Phase H: prefetch next gu; wave0 decoder || stage next At/S2 ----
    if (tl < 15) {
      const float* gp = gub + (size_t)((b << 4) + tl + 1) * 12288 + tid * 16;
      nxt.a = *(const f32x4*)(gp);     nxt.b = *(const f32x4*)(gp + 4);
      nxt.c = *(const f32x4*)(gp + 8); nxt.d = *(const f32x4*)(gp + 12);
    }
    if (w == 0) {
      int l = tid;
      float p = sh_pooled[l] * (1.f / 64.f);
      sh_pooled[l] = p;
      float a0 = ldf(db1, l), a1 = ldf(db1, l + 64);
      float c0 = 0.f, c1 = 0.f;
#pragma unroll 8
      for (int c = 0; c < 64; c += 2) {
        float p0 = sh_pooled[c], p1 = sh_pooled[c + 1];
        a0 += p0 * ldf(dW1, c * 128 + l);
        a1 += p0 * ldf(dW1, c * 128 + 64 + l);
        c0 += p1 * ldf(dW1, (c + 1) * 128 + l);
        c1 += p1 * ldf(dW1, (c + 1) * 128 + 64 + l);
      }
      sh_z1[l]      = fmaxf(a0 + c0, 0.f);
      sh_z1[l + 64] = fmaxf(a1 + c1, 0.f);
      float s0 = ldf(db2, l), s1 = 0.f, s2 = 0.f, s3 = 0.f;
#pragma unroll 8
      for (int c = 0; c < 128; c += 4) {
        s0 += sh_z1[c]     * ldf(dW2, c * 64 + l);
        s1 += sh_z1[c + 1] * ldf(dW2, (c + 1) * 64 + l);
        s2 += sh_z1[c + 2] * ldf(dW2, (c + 2) * 64 + l);
        s3 += sh_z1[c + 3] * ldf(dW2, (c + 3) * 64 + l);
      }
      sh_z2[l] = fmaxf(s0 + s1 + s2 + s3, 0.f);
      if (l < 6) {
        float acc = ldf(db3, l);
#pragma unroll 8
        for (int c = 0; c < 64; ++c) acc += sh_z2[c] * ldf(dW3, c * 6 + l);
        float val = acc * ldf(osc, l) + ldf(obi, l);
        stout((b * 128 + t) * 6 + l, val);
      }
    } else if (tl < 15) {
      stageSeq(t + 1, tl + 1, tid - 64, 704);
    }
    __syncthreads();
  };

#pragma unroll 1
  for (int tl = 0; tl < CH; tl += 2) {
    step(t0 + tl,     tl,     pA, pB);
    step(t0 + tl + 1, tl + 1, pB, pA);
  }
}

// ============================================================================
// Fallback: the verified monolithic kernel (used when workspace is too small)
// ============================================================================
__global__ __launch_bounds__(768, 1) void cfgcn(
    const void* __restrict__ frames, const void* __restrict__ adj,
    const void* __restrict__ hid0, const void* __restrict__ encW, const void* __restrict__ encb,
    const void* __restrict__ Wfh, const void* __restrict__ Wfu, const void* __restrict__ bfp,
    const void* __restrict__ Wgh, const void* __restrict__ Wgu, const void* __restrict__ bgp,
    const void* __restrict__ Wch, const void* __restrict__ Wcu, const void* __restrict__ bcp,
    const void* __restrict__ dW1, const void* __restrict__ db1,
    const void* __restrict__ dW2, const void* __restrict__ db2,
    const void* __restrict__ dW3, const void* __restrict__ db3,
    const void* __restrict__ osc, const void* __restrict__ obi,
    void* __restrict__ outv)
{
  __shared__ alignas(16) u16 lds[64000];
  u16* sh_h   = lds +     0;
  u16* sh_hT  = lds +  4608;
  u16* sh_At  = lds +  9216;
  u16* sh_AtT = lds + 13824;
  u16* sh_S2  = lds + 18432;
  u16* sh_xt  = lds + 23040;
  u16* sh_xtT = lds + 27648;
  u16* sh_Y1  = lds + 32256;
  u16* sh_Y2  = lds + 36864;
  u16* sh_G   = lds + 41472;
  u16* sh_fT  = lds + 55296;
  __shared__ float sh_biasG[192], sh_encB[64], sh_pooled[64], sh_z1[128], sh_z2[64];
  __shared__ int sh_flag;

  const int b    = blockIdx.x;
  const int tid  = threadIdx.x;
  const int w    = tid >> 6;
  const int lane = tid & 63;
  const int quad = lane >> 4;
  const int l15  = lane & 15;

  if (tid == 0) sh_flag = 0;
  for (int i = tid; i < 64000; i += 768) lds[i] = 0;
  __syncthreads();
  {
    int c = 0;
    const u16* fu = (const u16*)frames;
    for (int i = tid; i < 8192; i += 768) {
      u16 u = fu[i];
      c += ((u & 0x7F80u) >= 0x6000u) ? 1 : 0;
    }
    if (c) atomicAdd(&sh_flag, c);
  }
  __syncthreads();
  const bool isf32 = (sh_flag > 16);

  auto ldbf = [&](const void* p, int i) -> u16 {
    return isf32 ? f2bf(((const float*)p)[i]) : ((const u16*)p)[i];
  };
  auto ldf = [&](const void* p, int i) -> float {
    return isf32 ? ((const float*)p)[i] : bf2f(((const u16*)p)[i]);
  };
  auto fetch8 = [&](const void* p, int id) -> FragU {
    FragU f;
    if (!isf32) {
      f.q = ((const uint4*)p)[id];
    } else {
      const float4* fp = (const float4*)p;
      float4 lo = fp[2 * id], hi = fp[2 * id + 1];
      f.u[0] = f2bf(lo.x); f.u[1] = f2bf(lo.y); f.u[2] = f2bf(lo.z); f.u[3] = f2bf(lo.w);
      f.u[4] = f2bf(hi.x); f.u[5] = f2bf(hi.y); f.u[6] = f2bf(hi.z); f.u[7] = f2bf(hi.w);
    }
    return f;
  };
  auto stout = [&](int i, float v) {
    if (isf32) ((float*)outv)[i] = v; else ((u16*)outv)[i] = f2bf(v);
  };

  const void* Whp[3] = {Wfh, Wgh, Wch};
  const void* Wup[3] = {Wfu, Wgu, Wcu};
  const int gate = w >> 2;
  const int colg = ((w & 3) * 16) + l15;
  FragU wfrag[12];
#pragma unroll
  for (int kc = 0; kc < 12; ++kc) {
#pragma unroll
    for (int j = 0; j < 8; ++j) {
      int r = kc * 32 + quad * 8 + j;
      const void* src = (r < 192) ? Whp[gate] : Wup[gate];
      int rr = (r < 192) ? r : r - 192;
      wfrag[kc].u[j] = ldbf(src, (rr >> 6) * 4096 + (rr & 63) * 64 + colg);
    }
  }
  FragU efrag[4];
#pragma unroll
  for (int kc = 0; kc < 4; ++kc) {
#pragma unroll
    for (int j = 0; j < 8; ++j) {
      int c = kc * 32 + quad * 8 + j;
      efrag[kc].u[j] = ldbf(encW, c * 64 + ((w & 3) * 16 + l15));
    }
  }
  if (tid < 192) {
    const void* bp = (tid < 64) ? bfp : (tid < 128 ? bgp : bcp);
    sh_biasG[tid] = ldf(bp, tid & 63);
  }
  if (tid < 64) sh_encB[tid] = ldf(encb, tid);

  {
    const void* hg = isf32 ? (const void*)((const float*)hid0 + (size_t)b * 4096)
                           : (const void*)((const u16*)hid0 + (size_t)b * 4096);
    for (int st = tid; st < 512; st += 768) {
      FragU f = fetch8(hg, st);
      int n = st >> 3, d8 = (st & 7) * 8;
      *(uint4*)(sh_h + n * ST + d8) = f.q;
#pragma unroll
      for (int j = 0; j < 8; ++j) sh_hT[(d8 + j) * ST + n] = f.u[j];
    }
  }

  auto stage = [&](int tt, int st0, int stride) {
    const void* ag = isf32 ? (const void*)((const float*)adj + (size_t)(b * 128 + tt) * 4096)
                           : (const void*)((const u16*)adj + (size_t)(b * 128 + tt) * 4096);
    const void* fg = isf32 ? (const void*)((const float*)frames + (size_t)(b * 128 + tt) * 8192)
                           : (const void*)((const u16*)frames + (size_t)(b * 128 + tt) * 8192);
    for (int id = st0; id < 1536; id += stride) {
      if (id < 512) {
        FragU f = fetch8(ag, id);
        int r = id >> 3, c8 = (id & 7) * 8;
        *(uint4*)(sh_At + r * ST + c8) = f.q;
#pragma unroll
        for (int j = 0; j < 8; ++j) sh_AtT[(c8 + j) * ST + r] = f.u[j];
      } else {
        int k = id - 512;
        FragU f = fetch8(fg, k);
        int c = k >> 3, n8 = (k & 7) * 8;
#pragma unroll
        for (int j = 0; j < 8; ++j) sh_fT[(n8 + j) * FST + c] = f.u[j];
      }
    }
  };
  stage(0, tid, 768);

  auto tile64 = [&](const u16* A, const u16* BT, u16* C, int mt, int nt) {
    f32x4 acc = {0.f, 0.f, 0.f, 0.f};
    bf16x8 a0 = *(const bf16x8*)(A  + (mt * 16 + l15) * ST + quad * 8);
    bf16x8 b0 = *(const bf16x8*)(BT + (nt * 16 + l15) * ST + quad * 8);
    acc = __builtin_amdgcn_mfma_f32_16x16x32_bf16(a0, b0, acc, 0, 0, 0);
    bf16x8 a1 = *(const bf16x8*)(A  + (mt * 16 + l15) * ST + 32 + quad * 8);
    bf16x8 b1 = *(const bf16x8*)(BT + (nt * 16 + l15) * ST + 32 + quad * 8);
    acc = __builtin_amdgcn_mfma_f32_16x16x32_bf16(a1, b1, acc, 0, 0, 0);
    int cb = (mt * 16 + quad * 4) * ST + nt * 16 + l15;
    C[cb]          = f2bf(acc[0]);
    C[cb + ST]     = f2bf(acc[1]);
    C[cb + 2 * ST] = f2bf(acc[2]);
    C[cb + 3 * ST] = f2bf(acc[3]);
  };

  auto encTile = [&](int mt, int dt) {
    f32x4 acc = {0.f, 0.f, 0.f, 0.f};
#pragma unroll
    for (int kc = 0; kc < 4; ++kc) {
      bf16x8 a = *(const bf16x8*)(sh_fT + (mt * 16 + l15) * FST + kc * 32 + quad * 8);
      acc = __builtin_amdgcn_mfma_f32_16x16x32_bf16(a, efrag[kc].v, acc, 0, 0, 0);
    }
    int d = dt * 16 + l15;
    float eb = sh_encB[d];
#pragma unroll
    for (int r = 0; r < 4; ++r) {
      int n = mt * 16 + quad * 4 + r;
      u16 hv = f2bf(acc[r] + eb);
      sh_xt[n * ST + d]  = hv;
      sh_xtT[d * ST + n] = hv;
    }
  };

  f32x4 gacc[4];
  auto gstep = [&](const u16* buf, int koff, const FragU& wf) {
#pragma unroll
    for (int mt = 0; mt < 4; ++mt) {
      bf16x8 a = *(const bf16x8*)(buf + (mt * 16 + l15) * ST + koff + quad * 8);
      gacc[mt] = __builtin_amdgcn_mfma_f32_16x16x32_bf16(a, wf.v, gacc[mt], 0, 0, 0);
    }
  };

  __syncthreads();

  for (int t = 0; t < 128; ++t) {
    encTile(w >> 2, w & 3);
    if (w < 4) encTile(3, w);
    tile64(sh_At, sh_AtT, sh_S2, w >> 2, w & 3);
    if (w < 4) tile64(sh_At, sh_AtT, sh_S2, 3, w);
    __syncthreads();

#pragma unroll
    for (int i = 0; i < 3; ++i) {
      int id = w + 12 * i;
      if (id < 16)      tile64(sh_At, sh_xtT, sh_Y1, id >> 2, id & 3);
      else if (id < 32) tile64(sh_S2, sh_xtT, sh_Y2, (id - 16) >> 2, (id - 16) & 3);
    }
    __syncthreads();

    {
      f32x4 z = {0.f, 0.f, 0.f, 0.f};
      gacc[0] = z; gacc[1] = z; gacc[2] = z; gacc[3] = z;
    }
    gstep(sh_xt, 0, wfrag[6]);  gstep(sh_xt, 32, wfrag[7]);
    gstep(sh_Y1, 0, wfrag[8]);  gstep(sh_Y1, 32, wfrag[9]);
    gstep(sh_Y2, 0, wfrag[10]); gstep(sh_Y2, 32, wfrag[11]);
    __syncthreads();

#pragma unroll
    for (int i = 0; i < 3; ++i) {
      int id = w + 12 * i;
      if (id < 16)      tile64(sh_At, sh_hT, sh_Y1, id >> 2, id & 3);
      else if (id < 32) tile64(sh_S2, sh_hT, sh_Y2, (id - 16) >> 2, (id - 16) & 3);
    }
    __syncthreads();

    gstep(sh_h,  0, wfrag[0]); gstep(sh_h,  32, wfrag[1]);
    gstep(sh_Y1, 0, wfrag[2]); gstep(sh_Y1, 32, wfrag[3]);
    gstep(sh_Y2, 0, wfrag[4]); gstep(sh_Y2, 32, wfrag[5]);
    {
      float bias = sh_biasG[w * 16 + l15];
      u16* G = sh_G + gate * 4608;
      int col = (w & 3) * 16 + l15;
#pragma unroll
      for (int mt = 0; mt < 4; ++mt) {
#pragma unroll
        for (int r = 0; r < 4; ++r)
          G[(mt * 16 + quad * 4 + r) * ST + col] = f2bf(gacc[mt][r] + bias);
      }
    }
    if (tid < 64) sh_pooled[tid] = 0.f;
    __syncthreads();

    {
      float psum = 0.f;
      int d = tid & 63;
#pragma unroll
      for (int i = 0; i < 6; ++i) {
        int idx = tid + i * 768;
        if (idx < 4096) {
          int n = idx >> 6;
          float ff = bf2f(sh_G[n * ST + d]);
          float gg = bf2f(sh_G[4608 + n * ST + d]);
          float cc = bf2f(sh_G[9216 + n * ST + d]);
          float sig = 1.f / (1.f + __expf(-ff));
          float tg = 1.f - 2.f / (__expf(2.f * gg) + 1.f);
          float tc = 1.f - 2.f / (__expf(2.f * cc) + 1.f);
          float hn = sig * tg + (1.f - sig) * tc;
          u16 hv = f2bf(hn);
          sh_h[n * ST + d]  = hv;
          sh_hT[d * ST + n] = hv;
          psum += hn;
          if (t == 127) stout(49152 + (b << 12) + idx, hn);
        }
      }
      atomicAdd(&sh_pooled[d], psum);
    }
    __syncthreads();

    if (w == 0) {
      int l = tid;
      float p = sh_pooled[l] * (1.f / 64.f);
      sh_pooled[l] = p;
      float a0 = ldf(db1, l), a1 = ldf(db1, l + 64);
      float c0 = 0.f, c1 = 0.f;
#pragma unroll 8
      for (int c = 0; c < 64; c += 2) {
        float p0 = sh_pooled[c], p1 = sh_pooled[c + 1];
        a0 += p0 * ldf(dW1, c * 128 + l);
        a1 += p0 * ldf(dW1, c * 128 + 64 + l);
        c0 += p1 * ldf(dW1, (c + 1) * 128 + l);
        c1 += p1 * ldf(dW1, (c + 1) * 128 + 64 + l);
      }
      sh_z1[l]      = fmaxf(a0 + c0, 0.f);
      sh_z1[l + 64] = fmaxf(a1 + c1, 0.f);
      float s0 = ldf(db2, l), s1 = 0.f, s2 = 0.f, s3 = 0.f;
#pragma unroll 8
      for (int c = 0; c < 128; c += 4) {
        s0 += sh_z1[c]     * ldf(dW2, c * 64 + l);
        s1 += sh_z1[c + 1] * ldf(dW2, (c + 1) * 64 + l);
        s2 += sh_z1[c + 2] * ldf(dW2, (c + 2) * 64 + l);
        s3 += sh_z1[c + 3] * ldf(dW2, (c + 3) * 64 + l);
      }
      sh_z2[l] = fmaxf(s0 + s1 + s2 + s3, 0.f);
      if (l < 6) {
        float acc = ldf(db3, l);
#pragma unroll 8
        for (int c = 0; c < 64; ++c) acc += sh_z2[c] * ldf(dW3, c * 6 + l);
        float val = acc * ldf(osc, l) + ldf(obi, l);
        stout((b * 128 + t) * 6 + l, val);
      }
    } else if (t < 127) {
      stage(t + 1, tid - 64, 768 - 64);
    }
    __syncthreads();
  }
}

extern "C" void kernel_launch(void* const* d_in, const int* in_sizes, int n_in,
                              void* d_out, int out_size, void* d_ws, size_t ws_size,
                              hipStream_t stream) {
  (void)in_sizes; (void)n_in; (void)out_size;
  if (d_ws && ws_size >= (size_t)WS_NEED) {
    for (int c = 0; c < 8; ++c) {
      const int t0 = c * CH;
      cfgcn_pre<<<dim3(64 * CH), dim3(768), 0, stream>>>(
          d_in[0], d_in[1], d_in[3], d_in[4], d_in[6], d_in[9], d_in[12],
          (char*)d_ws, t0);
      cfgcn_seq<<<dim3(64), dim3(768), 0, stream>>>(
          d_in[0], d_in[1], d_in[2], d_in[5], d_in[8], d_in[11],
          d_in[7], d_in[10], d_in[13],
          d_in[14], d_in[15], d_in[16], d_in[17], d_in[18], d_in[19],
          d_in[20], d_in[21], d_out, (char*)d_ws, t0);
    }
  } else {
    cfgcn<<<dim3(64), dim3(768), 0, stream>>>(
        d_in[0], d_in[1], d_in[2], d_in[3], d_in[4], d_in[5], d_in[6], d_in[7],
        d_in[8], d_in[9], d_in[10], d_in[11], d_in[12], d_in[13], d_in[14], d_in[15],
        d_in[16], d_in[17], d_in[18], d_in[19], d_in[20], d_in[21], d_out);
  }
}

// Round 3
// 3017.741 us; speedup vs baseline: 1.2990x; 1.2990x over previous
//
#include <hip/hip_runtime.h>

typedef unsigned short u16;
typedef __bf16 bf16x8 __attribute__((ext_vector_type(8)));
typedef float f32x4 __attribute__((ext_vector_type(4)));

union FragU { bf16x8 v; u16 u[8]; uint4 q; };
struct Pf { f32x4 a, b, c, d; };   // 16 f32 gate-U partials per thread

__device__ __forceinline__ float bf2f(u16 u) {
  union { unsigned int i; float f; } x; x.i = ((unsigned int)u) << 16; return x.f;
}
__device__ __forceinline__ u16 f2bf(float f) {
  union { float f; unsigned int i; } x; x.f = f;
  return (u16)((x.i + 0x7FFFu + ((x.i >> 16) & 1u)) >> 16);
}

#define ST 72        // padded row stride (bf16 elems): 144B rows, 16B aligned
#define FST 136      // featsT stride (128 + 8)
#define CH 16        // timesteps per chunk
// workspace layout (bytes):
//   [0, 524288)            h carry, bf16 [64][4096]
//   [524288, 9961472)      S2 padded tiles, u16 [1024 rec][64*72]  (9216 B each)
//   [9961472, 60293120)    gu f32 [1024 rec][768 tid][16]          (49152 B each)
#define WS_S2_OFF 524288
#define WS_GU_OFF 9961472
#define WS_NEED   60293120

// ============================================================================
// Kernel 1: time-parallel prepass (unchanged from verified round-2 build).
// ============================================================================
__global__ __launch_bounds__(768) void cfgcn_pre(
    const void* __restrict__ frames, const void* __restrict__ adj,
    const void* __restrict__ encW, const void* __restrict__ encb,
    const void* __restrict__ Wfu, const void* __restrict__ Wgu, const void* __restrict__ Wcu,
    char* __restrict__ ws, int t0)
{
  __shared__ alignas(16) u16 lds[32256];
  u16* sh_Y1  = lds;            // 4608
  u16* sh_Y2  = lds + 4608;     // 4608   (Y1/Y2 overlap featsT: fT dead after phase B)
  u16* sh_fT  = lds;            // 64 x FST = 8704 (< 9216)
  u16* sh_At  = lds +  9216;
  u16* sh_AtT = lds + 13824;
  u16* sh_S2  = lds + 18432;
  u16* sh_xt  = lds + 23040;
  u16* sh_xtT = lds + 27648;
  __shared__ float sh_encB[64];
  __shared__ int sh_flag;

  const int bx  = blockIdx.x;          // rec index = b*CH + (t - t0)
  const int b   = bx >> 4;
  const int t   = t0 + (bx & 15);
  const int tid = threadIdx.x;
  const int w    = tid >> 6;
  const int lane = tid & 63;
  const int quad = lane >> 4;
  const int l15  = lane & 15;

  // ---- dtype detection ----
  if (tid == 0) sh_flag = 0;
  __syncthreads();
  {
    int c = 0;
    const u16* fu = (const u16*)frames;
    for (int i = tid; i < 8192; i += 768) {
      u16 u = fu[i];
      c += ((u & 0x7F80u) >= 0x6000u) ? 1 : 0;
    }
    if (c) atomicAdd(&sh_flag, c);
  }
  __syncthreads();
  const bool isf32 = (sh_flag > 16);

  auto ldbf = [&](const void* p, int i) -> u16 {
    return isf32 ? f2bf(((const float*)p)[i]) : ((const u16*)p)[i];
  };
  auto ldf = [&](const void* p, int i) -> float {
    return isf32 ? ((const float*)p)[i] : bf2f(((const u16*)p)[i]);
  };
  auto fetch8 = [&](const void* p, int id) -> FragU {
    FragU f;
    if (!isf32) {
      f.q = ((const uint4*)p)[id];
    } else {
      const float4* fp = (const float4*)p;
      float4 lo = fp[2 * id], hi = fp[2 * id + 1];
      f.u[0] = f2bf(lo.x); f.u[1] = f2bf(lo.y); f.u[2] = f2bf(lo.z); f.u[3] = f2bf(lo.w);
      f.u[4] = f2bf(hi.x); f.u[5] = f2bf(hi.y); f.u[6] = f2bf(hi.z); f.u[7] = f2bf(hi.w);
    }
    return f;
  };

  // ---- weight fragments: Wu cat rows 0..191 = {Wf/g/c}_u[k=0..2] ----
  const void* Wup[3] = {Wfu, Wgu, Wcu};
  const int gate = w >> 2;
  const int colg = ((w & 3) * 16) + l15;
  FragU wfrag[6];
#pragma unroll
  for (int kc = 0; kc < 6; ++kc) {
#pragma unroll
    for (int j = 0; j < 8; ++j) {
      int r = kc * 32 + quad * 8 + j;
      wfrag[kc].u[j] = ldbf(Wup[gate], (r >> 6) * 4096 + (r & 63) * 64 + colg);
    }
  }
  FragU efrag[4];
#pragma unroll
  for (int kc = 0; kc < 4; ++kc) {
#pragma unroll
    for (int j = 0; j < 8; ++j) {
      int c = kc * 32 + quad * 8 + j;
      efrag[kc].u[j] = ldbf(encW, c * 64 + ((w & 3) * 16 + l15));
    }
  }
  if (tid < 64) sh_encB[tid] = ldf(encb, tid);

  // ---- stage At + At^T + featsT ----
  {
    const void* ag = isf32 ? (const void*)((const float*)adj + (size_t)(b * 128 + t) * 4096)
                           : (const void*)((const u16*)adj + (size_t)(b * 128 + t) * 4096);
    const void* fg = isf32 ? (const void*)((const float*)frames + (size_t)(b * 128 + t) * 8192)
                           : (const void*)((const u16*)frames + (size_t)(b * 128 + t) * 8192);
    for (int id = tid; id < 1536; id += 768) {
      if (id < 512) {
        FragU f = fetch8(ag, id);
        int r = id >> 3, c8 = (id & 7) * 8;
        *(uint4*)(sh_At + r * ST + c8) = f.q;
#pragma unroll
        for (int j = 0; j < 8; ++j) sh_AtT[(c8 + j) * ST + r] = f.u[j];
      } else {
        int k = id - 512;
        FragU f = fetch8(fg, k);
        int c = k >> 3, n8 = (k & 7) * 8;
#pragma unroll
        for (int j = 0; j < 8; ++j) sh_fT[(n8 + j) * FST + c] = f.u[j];
      }
    }
  }
  __syncthreads();

  auto tile64 = [&](const u16* A, const u16* BT, u16* C, int mt, int nt) {
    f32x4 acc = {0.f, 0.f, 0.f, 0.f};
    bf16x8 a0 = *(const bf16x8*)(A  + (mt * 16 + l15) * ST + quad * 8);
    bf16x8 b0 = *(const bf16x8*)(BT + (nt * 16 + l15) * ST + quad * 8);
    acc = __builtin_amdgcn_mfma_f32_16x16x32_bf16(a0, b0, acc, 0, 0, 0);
    bf16x8 a1 = *(const bf16x8*)(A  + (mt * 16 + l15) * ST + 32 + quad * 8);
    bf16x8 b1 = *(const bf16x8*)(BT + (nt * 16 + l15) * ST + 32 + quad * 8);
    acc = __builtin_amdgcn_mfma_f32_16x16x32_bf16(a1, b1, acc, 0, 0, 0);
    int cb = (mt * 16 + quad * 4) * ST + nt * 16 + l15;
    C[cb]          = f2bf(acc[0]);
    C[cb + ST]     = f2bf(acc[1]);
    C[cb + 2 * ST] = f2bf(acc[2]);
    C[cb + 3 * ST] = f2bf(acc[3]);
  };
  auto encTile = [&](int mt, int dt) {
    f32x4 acc = {0.f, 0.f, 0.f, 0.f};
#pragma unroll
    for (int kc = 0; kc < 4; ++kc) {
      bf16x8 a = *(const bf16x8*)(sh_fT + (mt * 16 + l15) * FST + kc * 32 + quad * 8);
      acc = __builtin_amdgcn_mfma_f32_16x16x32_bf16(a, efrag[kc].v, acc, 0, 0, 0);
    }
    int d = dt * 16 + l15;
    float eb = sh_encB[d];
#pragma unroll
    for (int r = 0; r < 4; ++r) {
      int n = mt * 16 + quad * 4 + r;
      u16 hv = f2bf(acc[r] + eb);
      sh_xt[n * ST + d]  = hv;
      sh_xtT[d * ST + n] = hv;
    }
  };

  f32x4 gacc[4];
  auto gstep = [&](const u16* buf, int koff, const FragU& wf) {
#pragma unroll
    for (int mt = 0; mt < 4; ++mt) {
      bf16x8 a = *(const bf16x8*)(buf + (mt * 16 + l15) * ST + koff + quad * 8);
      gacc[mt] = __builtin_amdgcn_mfma_f32_16x16x32_bf16(a, wf.v, gacc[mt], 0, 0, 0);
    }
  };

  // ---- Phase B: encoder + S2 ----
  encTile(w >> 2, w & 3);
  if (w < 4) encTile(3, w);
  tile64(sh_At, sh_AtT, sh_S2, w >> 2, w & 3);
  if (w < 4) tile64(sh_At, sh_AtT, sh_S2, 3, w);
  __syncthreads();

  // ---- Phase C: yx1 = At@xt, yx2 = S2@xt ; dump S2 tile -> ws ----
#pragma unroll
  for (int i = 0; i < 3; ++i) {
    int id = w + 12 * i;
    if (id < 16)      tile64(sh_At, sh_xtT, sh_Y1, id >> 2, id & 3);
    else if (id < 32) tile64(sh_S2, sh_xtT, sh_Y2, (id - 16) >> 2, (id - 16) & 3);
  }
  {
    uint4* s2o = (uint4*)(ws + WS_S2_OFF + (size_t)bx * 9216);
    for (int id = tid; id < 576; id += 768) s2o[id] = ((const uint4*)sh_S2)[id];
  }
  __syncthreads();

  // ---- Phase D: gu = [xt,yx1,yx2] @ W_u  -> ws (f32, per-tid packed) ----
  {
    f32x4 z = {0.f, 0.f, 0.f, 0.f};
    gacc[0] = z; gacc[1] = z; gacc[2] = z; gacc[3] = z;
  }
  gstep(sh_xt, 0, wfrag[0]); gstep(sh_xt, 32, wfrag[1]);
  gstep(sh_Y1, 0, wfrag[2]); gstep(sh_Y1, 32, wfrag[3]);
  gstep(sh_Y2, 0, wfrag[4]); gstep(sh_Y2, 32, wfrag[5]);
  {
    float* gp = (float*)(ws + WS_GU_OFF + (size_t)bx * 49152) + tid * 16;
    *(f32x4*)(gp + 0)  = gacc[0];
    *(f32x4*)(gp + 4)  = gacc[1];
    *(f32x4*)(gp + 8)  = gacc[2];
    *(f32x4*)(gp + 12) = gacc[3];
  }
}

// ============================================================================
// Kernel 2: sequential recurrence. Decoder weights now live in LDS (staged
// once, f32, identical accumulation order -> bitwise-identical results).
// At/S2 single-buffered (stage in H is barrier-separated from reader E).
// LDS: 82944 B (u16 tiles) + ~69.7 KB f32 = ~152.6 KB.
// ============================================================================
__global__ __launch_bounds__(768, 1) void cfgcn_seq(
    const void* __restrict__ frames, const void* __restrict__ adj, const void* __restrict__ hid0,
    const void* __restrict__ Wfh, const void* __restrict__ Wgh, const void* __restrict__ Wch,
    const void* __restrict__ bfp, const void* __restrict__ bgp, const void* __restrict__ bcp,
    const void* __restrict__ dW1, const void* __restrict__ db1,
    const void* __restrict__ dW2, const void* __restrict__ db2,
    const void* __restrict__ dW3, const void* __restrict__ db3,
    const void* __restrict__ osc, const void* __restrict__ obi,
    void* __restrict__ outv, char* __restrict__ ws, int t0)
{
  __shared__ alignas(16) u16 lds[41472];
  u16* sh_h   = lds;            // 4608
  u16* sh_hT  = lds + 4608;
  u16* sh_Y1  = lds + 9216;
  u16* sh_Y2  = lds + 13824;
  u16* sh_G   = lds + 18432;    // 3*4608
  u16* sh_buf = lds + 32256;    // At 4608 + S2 4608 (single buffer)
  __shared__ float sh_dW1[8192];   // [c][l] 64x128
  __shared__ float sh_dW2[8192];   // [c][l] 128x64
  __shared__ float sh_dW3[384];    // [c][l] 64x6
  __shared__ float sh_biasG[192], sh_pooled[64], sh_z1[128], sh_z2[64];
  __shared__ float sh_db1[128], sh_db2[64], sh_db3[6], sh_osc[6], sh_obi[6];
  __shared__ int sh_flag;

  const int b    = blockIdx.x;
  const int tid  = threadIdx.x;
  const int w    = tid >> 6;
  const int lane = tid & 63;
  const int quad = lane >> 4;
  const int l15  = lane & 15;

  if (tid == 0) sh_flag = 0;
  __syncthreads();
  {
    int c = 0;
    const u16* fu = (const u16*)frames;
    for (int i = tid; i < 8192; i += 768) {
      u16 u = fu[i];
      c += ((u & 0x7F80u) >= 0x6000u) ? 1 : 0;
    }
    if (c) atomicAdd(&sh_flag, c);
  }
  __syncthreads();
  const bool isf32 = (sh_flag > 16);

  auto ldbf = [&](const void* p, int i) -> u16 {
    return isf32 ? f2bf(((const float*)p)[i]) : ((const u16*)p)[i];
  };
  auto ldf = [&](const void* p, int i) -> float {
    return isf32 ? ((const float*)p)[i] : bf2f(((const u16*)p)[i]);
  };
  auto fetch8 = [&](const void* p, int id) -> FragU {
    FragU f;
    if (!isf32) {
      f.q = ((const uint4*)p)[id];
    } else {
      const float4* fp = (const float4*)p;
      float4 lo = fp[2 * id], hi = fp[2 * id + 1];
      f.u[0] = f2bf(lo.x); f.u[1] = f2bf(lo.y); f.u[2] = f2bf(lo.z); f.u[3] = f2bf(lo.w);
      f.u[4] = f2bf(hi.x); f.u[5] = f2bf(hi.y); f.u[6] = f2bf(hi.z); f.u[7] = f2bf(hi.w);
    }
    return f;
  };
  auto stout = [&](int i, float v) {
    if (isf32) ((float*)outv)[i] = v; else ((u16*)outv)[i] = f2bf(v);
  };

  // ---- W_h fragments (rows 0..191 = {Wf/g/c}_h[k=0..2]) ----
  const void* Whp[3] = {Wfh, Wgh, Wch};
  const int gate = w >> 2;
  const int colg = ((w & 3) * 16) + l15;
  FragU wfrag[6];
#pragma unroll
  for (int kc = 0; kc < 6; ++kc) {
#pragma unroll
    for (int j = 0; j < 8; ++j) {
      int r = kc * 32 + quad * 8 + j;
      wfrag[kc].u[j] = ldbf(Whp[gate], (r >> 6) * 4096 + (r & 63) * 64 + colg);
    }
  }
  if (tid < 192) {
    const void* bp = (tid < 64) ? bfp : (tid < 128 ? bgp : bcp);
    sh_biasG[tid] = ldf(bp, tid & 63);
  }

  // ---- one-time decoder weight staging (f32 in LDS; values identical to
  //      what the per-step ldf() calls used to produce) ----
  for (int i = tid; i < 8192; i += 768) sh_dW1[i] = ldf(dW1, i);
  for (int i = tid; i < 8192; i += 768) sh_dW2[i] = ldf(dW2, i);
  if (tid < 384) sh_dW3[tid] = ldf(dW3, tid);
  if (tid < 128) sh_db1[tid] = ldf(db1, tid);
  if (tid < 64)  sh_db2[tid] = ldf(db2, tid);
  if (tid < 6) {
    sh_db3[tid] = ldf(db3, tid);
    sh_osc[tid] = ldf(osc, tid);
    sh_obi[tid] = ldf(obi, tid);
  }

  u16* wsh = (u16*)ws;   // h carry (bf16)

  // ---- stage h (chunk 0: hid0 input; else: carried state) ----
  for (int st = tid; st < 512; st += 768) {
    FragU f;
    if (t0 == 0) {
      const void* hg = isf32 ? (const void*)((const float*)hid0 + (size_t)b * 4096)
                             : (const void*)((const u16*)hid0 + (size_t)b * 4096);
      f = fetch8(hg, st);
    } else {
      f.q = ((const uint4*)(wsh + (size_t)b * 4096))[st];
    }
    int n = st >> 3, d8 = (st & 7) * 8;
    *(uint4*)(sh_h + n * ST + d8) = f.q;
#pragma unroll
    for (int j = 0; j < 8; ++j) sh_hT[(d8 + j) * ST + n] = f.u[j];
  }

  auto tile64 = [&](const u16* A, const u16* BT, u16* C, int mt, int nt) {
    f32x4 acc = {0.f, 0.f, 0.f, 0.f};
    bf16x8 a0 = *(const bf16x8*)(A  + (mt * 16 + l15) * ST + quad * 8);
    bf16x8 b0 = *(const bf16x8*)(BT + (nt * 16 + l15) * ST + quad * 8);
    acc = __builtin_amdgcn_mfma_f32_16x16x32_bf16(a0, b0, acc, 0, 0, 0);
    bf16x8 a1 = *(const bf16x8*)(A  + (mt * 16 + l15) * ST + 32 + quad * 8);
    bf16x8 b1 = *(const bf16x8*)(BT + (nt * 16 + l15) * ST + 32 + quad * 8);
    acc = __builtin_amdgcn_mfma_f32_16x16x32_bf16(a1, b1, acc, 0, 0, 0);
    int cb = (mt * 16 + quad * 4) * ST + nt * 16 + l15;
    C[cb]          = f2bf(acc[0]);
    C[cb + ST]     = f2bf(acc[1]);
    C[cb + 2 * ST] = f2bf(acc[2]);
    C[cb + 3 * ST] = f2bf(acc[3]);
  };

  f32x4 gacc[4];
  auto gstep = [&](const u16* buf, int koff, const FragU& wf) {
#pragma unroll
    for (int mt = 0; mt < 4; ++mt) {
      bf16x8 a = *(const bf16x8*)(buf + (mt * 16 + l15) * ST + koff + quad * 8);
      gacc[mt] = __builtin_amdgcn_mfma_f32_16x16x32_bf16(a, wf.v, gacc[mt], 0, 0, 0);
    }
  };

  // stage At (from adj, dtype-converted) + S2 (tile image from ws) for step tln
  auto stageSeq = [&](int tn, int tln, int st0, int stride) {
    u16* dAt = sh_buf;
    u16* dS2 = dAt + 4608;
    const void* ag = isf32 ? (const void*)((const float*)adj + (size_t)(b * 128 + tn) * 4096)
                           : (const void*)((const u16*)adj + (size_t)(b * 128 + tn) * 4096);
    const uint4* s2g = (const uint4*)(ws + WS_S2_OFF + (size_t)((b << 4) + tln) * 9216);
    for (int id = st0; id < 1088; id += stride) {
      if (id < 512) {
        FragU f = fetch8(ag, id);
        int r = id >> 3, c8 = (id & 7) * 8;
        *(uint4*)(dAt + r * ST + c8) = f.q;
      } else {
        ((uint4*)dS2)[id - 512] = s2g[id - 512];
      }
    }
  };

  const float* gub = (const float*)(ws + WS_GU_OFF);
  Pf pA, pB;
  stageSeq(t0, 0, tid, 768);
  {
    const float* gp = gub + (size_t)(b << 4) * 12288 + tid * 16;
    pA.a = *(const f32x4*)(gp);     pA.b = *(const f32x4*)(gp + 4);
    pA.c = *(const f32x4*)(gp + 8); pA.d = *(const f32x4*)(gp + 12);
  }
  __syncthreads();

  auto step = [&](int t, int tl, Pf& use, Pf& nxt) {
    u16* At  = sh_buf;
    u16* S2v = At + 4608;

    // ---- Phase E: seed gacc from gu; h-part of gate; yh1/yh2 ----
    gacc[0] = use.a; gacc[1] = use.b; gacc[2] = use.c; gacc[3] = use.d;
    gstep(sh_h, 0, wfrag[0]); gstep(sh_h, 32, wfrag[1]);
#pragma unroll
    for (int i = 0; i < 3; ++i) {
      int id = w + 12 * i;
      if (id < 16)      tile64(At,  sh_hT, sh_Y1, id >> 2, id & 3);
      else if (id < 32) tile64(S2v, sh_hT, sh_Y2, (id - 16) >> 2, (id - 16) & 3);
    }
    __syncthreads();

    // ---- Phase F: gate += [yh1,yh2]@W_h ; preacts (+bias) -> sh_G ----
    gstep(sh_Y1, 0, wfrag[2]); gstep(sh_Y1, 32, wfrag[3]);
    gstep(sh_Y2, 0, wfrag[4]); gstep(sh_Y2, 32, wfrag[5]);
    {
      float bias = sh_biasG[w * 16 + l15];
      u16* G = sh_G + gate * 4608;
      int col = (w & 3) * 16 + l15;
#pragma unroll
      for (int mt = 0; mt < 4; ++mt) {
#pragma unroll
        for (int r = 0; r < 4; ++r)
          G[(mt * 16 + quad * 4 + r) * ST + col] = f2bf(gacc[mt][r] + bias);
      }
    }
    if (tid < 64) sh_pooled[tid] = 0.f;
    __syncthreads();

    // ---- Phase G: h_new + pooled ----
    {
      float psum = 0.f;
      int d = tid & 63;
#pragma unroll
      for (int i = 0; i < 6; ++i) {
        int idx = tid + i * 768;
        if (idx < 4096) {
          int n = idx >> 6;
          float ff = bf2f(sh_G[n * ST + d]);
          float gg = bf2f(sh_G[4608 + n * ST + d]);
          float cc = bf2f(sh_G[9216 + n * ST + d]);
          float sig = 1.f / (1.f + __expf(-ff));
          float tg = 1.f - 2.f / (__expf(2.f * gg) + 1.f);
          float tc = 1.f - 2.f / (__expf(2.f * cc) + 1.f);
          float hn = sig * tg + (1.f - sig) * tc;
          u16 hv = f2bf(hn);
          sh_h[n * ST + d]  = hv;
          sh_hT[d * ST + n] = hv;
          psum += hn;
          if (t == 127) stout(49152 + (b << 12) + idx, hn);     // final_hidden
          if (tl == 15) wsh[(size_t)b * 4096 + idx] = hv;       // h carry
        }
      }
      atomicAdd(&sh_pooled[d], psum);
    }
    __syncthreads();

    // ---- Phase H: prefetch next gu; wave0 decoder (LDS weights) ||
    //      waves 1..11 stage next At/S2 ----
    if (tl < 15) {
      const float* gp = gub + (size_t)((b << 4) + tl + 1) * 12288 + tid * 16;
      nxt.a = *(const f32x4*)(gp);     nxt.b = *(const f32x4*)(gp + 4);
      nxt.c = *(const f32x4*)(gp + 8); nxt.d = *(const f32x4*)(gp + 12);
    }
    if (w == 0) {
      int l = tid;
      float p = sh_pooled[l] * (1.f / 64.f);
      sh_pooled[l] = p;   // same-wave write->read ordering
      float a0 = sh_db1[l], a1 = sh_db1[l + 64];
      float c0 = 0.f, c1 = 0.f;
#pragma unroll 8
      for (int c = 0; c < 64; c += 2) {
        float p0 = sh_pooled[c], p1 = sh_pooled[c + 1];
        a0 += p0 * sh_dW1[c * 128 + l];
        a1 += p0 * sh_dW1[c * 128 + 64 + l];
        c0 += p1 * sh_dW1[(c + 1) * 128 + l];
        c1 += p1 * sh_dW1[(c + 1) * 128 + 64 + l];
      }
      sh_z1[l]      = fmaxf(a0 + c0, 0.f);
      sh_z1[l + 64] = fmaxf(a1 + c1, 0.f);
      float s0 = sh_db2[l], s1 = 0.f, s2 = 0.f, s3 = 0.f;
#pragma unroll 8
      for (int c = 0; c < 128; c += 4) {
        s0 += sh_z1[c]     * sh_dW2[c * 64 + l];
        s1 += sh_z1[c + 1] * sh_dW2[(c + 1) * 64 + l];
        s2 += sh_z1[c + 2] * sh_dW2[(c + 2) * 64 + l];
        s3 += sh_z1[c + 3] * sh_dW2[(c + 3) * 64 + l];
      }
      sh_z2[l] = fmaxf(s0 + s1 + s2 + s3, 0.f);
      if (l < 6) {
        float acc = sh_db3[l];
#pragma unroll 8
        for (int c = 0; c < 64; ++c) acc += sh_z2[c] * sh_dW3[c * 6 + l];
        float val = acc * sh_osc[l] + sh_obi[l];
        stout((b * 128 + t) * 6 + l, val);   // controls
      }
    } else if (tl < 15) {
      stageSeq(t + 1, tl + 1, tid - 64, 704);
    }
    __syncthreads();
  };

#pragma unroll 1
  for (int tl = 0; tl < CH; tl += 2) {
    step(t0 + tl,     tl,     pA, pB);
    step(t0 + tl + 1, tl + 1, pB, pA);
  }
}

// ============================================================================
// Fallback: the verified monolithic kernel (used when workspace is too small)
// ============================================================================
__global__ __launch_bounds__(768, 1) void cfgcn(
    const void* __restrict__ frames, const void* __restrict__ adj,
    const void* __restrict__ hid0, const void* __restrict__ encW, const void* __restrict__ encb,
    const void* __restrict__ Wfh, const void* __restrict__ Wfu, const void* __restrict__ bfp,
    const void* __restrict__ Wgh, const void* __restrict__ Wgu, const void* __restrict__ bgp,
    const void* __restrict__ Wch, const void* __restrict__ Wcu, const void* __restrict__ bcp,
    const void* __restrict__ dW1, const void* __restrict__ db1,
    const void* __restrict__ dW2, const void* __restrict__ db2,
    const void* __restrict__ dW3, const void* __restrict__ db3,
    const void* __restrict__ osc, const void* __restrict__ obi,
    void* __restrict__ outv)
{
  __shared__ alignas(16) u16 lds[64000];
  u16* sh_h   = lds +     0;
  u16* sh_hT  = lds +  4608;
  u16* sh_At  = lds +  9216;
  u16* sh_AtT = lds + 13824;
  u16* sh_S2  = lds + 18432;
  u16* sh_xt  = lds + 23040;
  u16* sh_xtT = lds + 27648;
  u16* sh_Y1  = lds + 32256;
  u16* sh_Y2  = lds + 36864;
  u16* sh_G   = lds + 41472;
  u16* sh_fT  = lds + 55296;
  __shared__ float sh_biasG[192], sh_encB[64], sh_pooled[64], sh_z1[128], sh_z2[64];
  __shared__ int sh_flag;

  const int b    = blockIdx.x;
  const int tid  = threadIdx.x;
  const int w    = tid >> 6;
  const int lane = tid & 63;
  const int quad = lane >> 4;
  const int l15  = lane & 15;

  if (tid == 0) sh_flag = 0;
  for (int i = tid; i < 64000; i += 768) lds[i] = 0;
  __syncthreads();
  {
    int c = 0;
    const u16* fu = (const u16*)frames;
    for (int i = tid; i < 8192; i += 768) {
      u16 u = fu[i];
      c += ((u & 0x7F80u) >= 0x6000u) ? 1 : 0;
    }
    if (c) atomicAdd(&sh_flag, c);
  }
  __syncthreads();
  const bool isf32 = (sh_flag > 16);

  auto ldbf = [&](const void* p, int i) -> u16 {
    return isf32 ? f2bf(((const float*)p)[i]) : ((const u16*)p)[i];
  };
  auto ldf = [&](const void* p, int i) -> float {
    return isf32 ? ((const float*)p)[i] : bf2f(((const u16*)p)[i]);
  };
  auto fetch8 = [&](const void* p, int id) -> FragU {
    FragU f;
    if (!isf32) {
      f.q = ((const uint4*)p)[id];
    } else {
      const float4* fp = (const float4*)p;
      float4 lo = fp[2 * id], hi = fp[2 * id + 1];
      f.u[0] = f2bf(lo.x); f.u[1] = f2bf(lo.y); f.u[2] = f2bf(lo.z); f.u[3] = f2bf(lo.w);
      f.u[4] = f2bf(hi.x); f.u[5] = f2bf(hi.y); f.u[6] = f2bf(hi.z); f.u[7] = f2bf(hi.w);
    }
    return f;
  };
  auto stout = [&](int i, float v) {
    if (isf32) ((float*)outv)[i] = v; else ((u16*)outv)[i] = f2bf(v);
  };

  const void* Whp[3] = {Wfh, Wgh, Wch};
  const void* Wup[3] = {Wfu, Wgu, Wcu};
  const int gate = w >> 2;
  const int colg = ((w & 3) * 16) + l15;
  FragU wfrag[12];
#pragma unroll
  for (int kc = 0; kc < 12; ++kc) {
#pragma unroll
    for (int j = 0; j < 8; ++j) {
      int r = kc * 32 + quad * 8 + j;
      const void* src = (r < 192) ? Whp[gate] : Wup[gate];
      int rr = (r < 192) ? r : r - 192;
      wfrag[kc].u[j] = ldbf(src, (rr >> 6) * 4096 + (rr & 63) * 64 + colg);
    }
  }
  FragU efrag[4];
#pragma unroll
  for (int kc = 0; kc < 4; ++kc) {
#pragma unroll
    for (int j = 0; j < 8; ++j) {
      int c = kc * 32 + quad * 8 + j;
      efrag[kc].u[j] = ldbf(encW, c * 64 + ((w & 3) * 16 + l15));
    }
  }
  if (tid < 192) {
    const void* bp = (tid < 64) ? bfp : (tid < 128 ? bgp : bcp);
    sh_biasG[tid] = ldf(bp, tid & 63);
  }
  if (tid < 64) sh_encB[tid] = ldf(encb, tid);

  {
    const void* hg = isf32 ? (const void*)((const float*)hid0 + (size_t)b * 4096)
                           : (const void*)((const u16*)hid0 + (size_t)b * 4096);
    for (int st = tid; st < 512; st += 768) {
      FragU f = fetch8(hg, st);
      int n = st >> 3, d8 = (st & 7) * 8;
      *(uint4*)(sh_h + n * ST + d8) = f.q;
#pragma unroll
      for (int j = 0; j < 8; ++j) sh_hT[(d8 + j) * ST + n] = f.u[j];
    }
  }

  auto stage = [&](int tt, int st0, int stride) {
    const void* ag = isf32 ? (const void*)((const float*)adj + (size_t)(b * 128 + tt) * 4096)
                           : (const void*)((const u16*)adj + (size_t)(b * 128 + tt) * 4096);
    const void* fg = isf32 ? (const void*)((const float*)frames + (size_t)(b * 128 + tt) * 8192)
                           : (const void*)((const u16*)frames + (size_t)(b * 128 + tt) * 8192);
    for (int id = st0; id < 1536; id += stride) {
      if (id < 512) {
        FragU f = fetch8(ag, id);
        int r = id >> 3, c8 = (id & 7) * 8;
        *(uint4*)(sh_At + r * ST + c8) = f.q;
#pragma unroll
        for (int j = 0; j < 8; ++j) sh_AtT[(c8 + j) * ST + r] = f.u[j];
      } else {
        int k = id - 512;
        FragU f = fetch8(fg, k);
        int c = k >> 3, n8 = (k & 7) * 8;
#pragma unroll
        for (int j = 0; j < 8; ++j) sh_fT[(n8 + j) * FST + c] = f.u[j];
      }
    }
  };
  stage(0, tid, 768);

  auto tile64 = [&](const u16* A, const u16* BT, u16* C, int mt, int nt) {
    f32x4 acc = {0.f, 0.f, 0.f, 0.f};
    bf16x8 a0 = *(const bf16x8*)(A  + (mt * 16 + l15) * ST + quad * 8);
    bf16x8 b0 = *(const bf16x8*)(BT + (nt * 16 + l15) * ST + quad * 8);
    acc = __builtin_amdgcn_mfma_f32_16x16x32_bf16(a0, b0, acc, 0, 0, 0);
    bf16x8 a1 = *(const bf16x8*)(A  + (mt * 16 + l15) * ST + 32 + quad * 8);
    bf16x8 b1 = *(const bf16x8*)(BT + (nt * 16 + l15) * ST + 32 + quad * 8);
    acc = __builtin_amdgcn_mfma_f32_16x16x32_bf16(a1, b1, acc, 0, 0, 0);
    int cb = (mt * 16 + quad * 4) * ST + nt * 16 + l15;
    C[cb]          = f2bf(acc[0]);
    C[cb + ST]     = f2bf(acc[1]);
    C[cb + 2 * ST] = f2bf(acc[2]);
    C[cb + 3 * ST] = f2bf(acc[3]);
  };

  auto encTile = [&](int mt, int dt) {
    f32x4 acc = {0.f, 0.f, 0.f, 0.f};
#pragma unroll
    for (int kc = 0; kc < 4; ++kc) {
      bf16x8 a = *(const bf16x8*)(sh_fT + (mt * 16 + l15) * FST + kc * 32 + quad * 8);
      acc = __builtin_amdgcn_mfma_f32_16x16x32_bf16(a, efrag[kc].v, acc, 0, 0, 0);
    }
    int d = dt * 16 + l15;
    float eb = sh_encB[d];
#pragma unroll
    for (int r = 0; r < 4; ++r) {
      int n = mt * 16 + quad * 4 + r;
      u16 hv = f2bf(acc[r] + eb);
      sh_xt[n * ST + d]  = hv;
      sh_xtT[d * ST + n] = hv;
    }
  };

  f32x4 gacc[4];
  auto gstep = [&](const u16* buf, int koff, const FragU& wf) {
#pragma unroll
    for (int mt = 0; mt < 4; ++mt) {
      bf16x8 a = *(const bf16x8*)(buf + (mt * 16 + l15) * ST + koff + quad * 8);
      gacc[mt] = __builtin_amdgcn_mfma_f32_16x16x32_bf16(a, wf.v, gacc[mt], 0, 0, 0);
    }
  };

  __syncthreads();

  for (int t = 0; t < 128; ++t) {
    encTile(w >> 2, w & 3);
    if (w < 4) encTile(3, w);
    tile64(sh_At, sh_AtT, sh_S2, w >> 2, w & 3);
    if (w < 4) tile64(sh_At, sh_AtT, sh_S2, 3, w);
    __syncthreads();

#pragma unroll
    for (int i = 0; i < 3; ++i) {
      int id = w + 12 * i;
      if (id < 16)      tile64(sh_At, sh_xtT, sh_Y1, id >> 2, id & 3);
      else if (id < 32) tile64(sh_S2, sh_xtT, sh_Y2, (id - 16) >> 2, (id - 16) & 3);
    }
    __syncthreads();

    {
      f32x4 z = {0.f, 0.f, 0.f, 0.f};
      gacc[0] = z; gacc[1] = z; gacc[2] = z; gacc[3] = z;
    }
    gstep(sh_xt, 0, wfrag[6]);  gstep(sh_xt, 32, wfrag[7]);
    gstep(sh_Y1, 0, wfrag[8]);  gstep(sh_Y1, 32, wfrag[9]);
    gstep(sh_Y2, 0, wfrag[10]); gstep(sh_Y2, 32, wfrag[11]);
    __syncthreads();

#pragma unroll
    for (int i = 0; i < 3; ++i) {
      int id = w + 12 * i;
      if (id < 16)      tile64(sh_At, sh_hT, sh_Y1, id >> 2, id & 3);
      else if (id < 32) tile64(sh_S2, sh_hT, sh_Y2, (id - 16) >> 2, (id - 16) & 3);
    }
    __syncthreads();

    gstep(sh_h,  0, wfrag[0]); gstep(sh_h,  32, wfrag[1]);
    gstep(sh_Y1, 0, wfrag[2]); gstep(sh_Y1, 32, wfrag[3]);
    gstep(sh_Y2, 0, wfrag[4]); gstep(sh_Y2, 32, wfrag[5]);
    {
      float bias = sh_biasG[w * 16 + l15];
      u16* G = sh_G + gate * 4608;
      int col = (w & 3) * 16 + l15;
#pragma unroll
      for (int mt = 0; mt < 4; ++mt) {
#pragma unroll
        for (int r = 0; r < 4; ++r)
          G[(mt * 16 + quad * 4 + r) * ST + col] = f2bf(gacc[mt][r] + bias);
      }
    }
    if (tid < 64) sh_pooled[tid] = 0.f;
    __syncthreads();

    {
      float psum = 0.f;
      int d = tid & 63;
#pragma unroll
      for (int i = 0; i < 6; ++i) {
        int idx = tid + i * 768;
        if (idx < 4096) {
          int n = idx >> 6;
          float ff = bf2f(sh_G[n * ST + d]);
          float gg = bf2f(sh_G[4608 + n * ST + d]);
          float cc = bf2f(sh_G[9216 + n * ST + d]);
          float sig = 1.f / (1.f + __expf(-ff));
          float tg = 1.f - 2.f / (__expf(2.f * gg) + 1.f);
          float tc = 1.f - 2.f / (__expf(2.f * cc) + 1.f);
          float hn = sig * tg + (1.f - sig) * tc;
          u16 hv = f2bf(hn);
          sh_h[n * ST + d]  = hv;
          sh_hT[d * ST + n] = hv;
          psum += hn;
          if (t == 127) stout(49152 + (b << 12) + idx, hn);
        }
      }
      atomicAdd(&sh_pooled[d], psum);
    }
    __syncthreads();

    if (w == 0) {
      int l = tid;
      float p = sh_pooled[l] * (1.f / 64.f);
      sh_pooled[l] = p;
      float a0 = ldf(db1, l), a1 = ldf(db1, l + 64);
      float c0 = 0.f, c1 = 0.f;
#pragma unroll 8
      for (int c = 0; c < 64; c += 2) {
        float p0 = sh_pooled[c], p1 = sh_pooled[c + 1];
        a0 += p0 * ldf(dW1, c * 128 + l);
        a1 += p0 * ldf(dW1, c * 128 + 64 + l);
        c0 += p1 * ldf(dW1, (c + 1) * 128 + l);
        c1 += p1 * ldf(dW1, (c + 1) * 128 + 64 + l);
      }
      sh_z1[l]      = fmaxf(a0 + c0, 0.f);
      sh_z1[l + 64] = fmaxf(a1 + c1, 0.f);
      float s0 = ldf(db2, l), s1 = 0.f, s2 = 0.f, s3 = 0.f;
#pragma unroll 8
      for (int c = 0; c < 128; c += 4) {
        s0 += sh_z1[c]     * ldf(dW2, c * 64 + l);
        s1 += sh_z1[c + 1] * ldf(dW2, (c + 1) * 64 + l);
        s2 += sh_z1[c + 2] * ldf(dW2, (c + 2) * 64 + l);
        s3 += sh_z1[c + 3] * ldf(dW2, (c + 3) * 64 + l);
      }
      sh_z2[l] = fmaxf(s0 + s1 + s2 + s3, 0.f);
      if (l < 6) {
        float acc = ldf(db3, l);
#pragma unroll 8
        for (int c = 0; c < 64; ++c) acc += sh_z2[c] * ldf(dW3, c * 6 + l);
        float val = acc * ldf(osc, l) + ldf(obi, l);
        stout((b * 128 + t) * 6 + l, val);
      }
    } else if (t < 127) {
      stage(t + 1, tid - 64, 768 - 64);
    }
    __syncthreads();
  }
}

extern "C" void kernel_launch(void* const* d_in, const int* in_sizes, int n_in,
                              void* d_out, int out_size, void* d_ws, size_t ws_size,
                              hipStream_t stream) {
  (void)in_sizes; (void)n_in; (void)out_size;
  if (d_ws && ws_size >= (size_t)WS_NEED) {
    for (int c = 0; c < 8; ++c) {
      const int t0 = c * CH;
      cfgcn_pre<<<dim3(64 * CH), dim3(768), 0, stream>>>(
          d_in[0], d_in[1], d_in[3], d_in[4], d_in[6], d_in[9], d_in[12],
          (char*)d_ws, t0);
      cfgcn_seq<<<dim3(64), dim3(768), 0, stream>>>(
          d_in[0], d_in[1], d_in[2], d_in[5], d_in[8], d_in[11],
          d_in[7], d_in[10], d_in[13],
          d_in[14], d_in[15], d_in[16], d_in[17], d_in[18], d_in[19],
          d_in[20], d_in[21], d_out, (char*)d_ws, t0);
    }
  } else {
    cfgcn<<<dim3(64), dim3(768), 0, stream>>>(
        d_in[0], d_in[1], d_in[2], d_in[3], d_in[4], d_in[5], d_in[6], d_in[7],
        d_in[8], d_in[9], d_in[10], d_in[11], d_in[12], d_in[13], d_in[14], d_in[15],
        d_in[16], d_in[17], d_in[18], d_in[19], d_in[20], d_in[21], d_out);
  }
}

// Round 5
// 2132.392 us; speedup vs baseline: 1.8384x; 1.4152x over previous
//
#include <hip/hip_runtime.h>

typedef unsigned short u16;
typedef __bf16 bf16x8 __attribute__((ext_vector_type(8)));
typedef float f32x4 __attribute__((ext_vector_type(4)));
typedef unsigned long long u64;

union FragU { bf16x8 v; u16 u[8]; uint4 q; };
struct Pf { f32x4 a, b, c, d; };   // 16 f32 gate-U partials per thread

__device__ __forceinline__ float bf2f(u16 u) {
  union { unsigned int i; float f; } x; x.i = ((unsigned int)u) << 16; return x.f;
}
__device__ __forceinline__ u16 f2bf(float f) {
  union { float f; unsigned int i; } x; x.f = f;
  return (u16)((x.i + 0x7FFFu + ((x.i >> 16) & 1u)) >> 16);
}

#define ST 72        // padded row stride (bf16 elems)
#define FST 136      // featsT stride (128 + 8)
#define CH 16        // timesteps per chunk
// ---- compact layout (serialized path, 57.5 MB) ----
#define WS_S2_OFF 524288
#define WS_GU_OFF 9961472
#define WS_NEED   60293120
// ---- slotted layout (pipelined path, 114.5 MB) ----
#define P_S2_OFF  524288
#define P_S2_SLOT 9437184          // 1024 rec * 9216 B
#define P_GU_OFF  19398656
#define P_GU_SLOT 50331648         // 1024 rec * 49152 B
#define WS_NEED_PIPE 120061952

// ============================================================================
// dtype detection (uniform per block; two barriers)
// ============================================================================
__device__ __forceinline__ bool detect_f32(const void* frames, int* sh_flag) {
  const int tid = threadIdx.x;
  if (tid == 0) *sh_flag = 0;
  __syncthreads();
  int c = 0;
  const u16* fu = (const u16*)frames;
  for (int i = tid; i < 8192; i += 768) {
    u16 u = fu[i];
    c += ((u & 0x7F80u) >= 0x6000u) ? 1 : 0;
  }
  if (c) atomicAdd(sh_flag, c);
  __syncthreads();
  return *sh_flag > 16;
}

// ============================================================================
// PRE body: grid-stride over chunk records rec in [rec0, 1024) step recStride.
// Per record: xt = feats@encW+b, S2 = At@At, yx1 = At@xt, yx2 = S2@xt,
//   gu = xt@Wu0 + yx1@Wu1 + yx2@Wu2 (f32, per-tid packed) -> ws
//   S2 (bf16 padded tile image) -> ws
// Weight fragments loaded ONCE per block (amortized over records).
// ============================================================================
__device__ void pre_body(
    const void* __restrict__ frames, const void* __restrict__ adj,
    const void* __restrict__ encW, const void* __restrict__ encb,
    const void* __restrict__ Wfu, const void* __restrict__ Wgu, const void* __restrict__ Wcu,
    char* __restrict__ ws, u64 s2_base, u64 gu_base, int t0,
    int rec0, int recStride,
    u16* lds, float* sh_encB, int* sh_flag)
{
  u16* sh_Y1  = lds;            // 4608
  u16* sh_Y2  = lds + 4608;     // 4608   (Y1/Y2 overlap featsT)
  u16* sh_fT  = lds;            // 64 x FST = 8704 (< 9216)
  u16* sh_At  = lds +  9216;
  u16* sh_AtT = lds + 13824;
  u16* sh_S2  = lds + 18432;
  u16* sh_xt  = lds + 23040;
  u16* sh_xtT = lds + 27648;

  const int tid = threadIdx.x;
  const int w    = tid >> 6;
  const int lane = tid & 63;
  const int quad = lane >> 4;
  const int l15  = lane & 15;

  const bool isf32 = detect_f32(frames, sh_flag);

  auto ldbf = [&](const void* p, int i) -> u16 {
    return isf32 ? f2bf(((const float*)p)[i]) : ((const u16*)p)[i];
  };
  auto ldf = [&](const void* p, int i) -> float {
    return isf32 ? ((const float*)p)[i] : bf2f(((const u16*)p)[i]);
  };
  auto fetch8 = [&](const void* p, int id) -> FragU {
    FragU f;
    if (!isf32) {
      f.q = ((const uint4*)p)[id];
    } else {
      const float4* fp = (const float4*)p;
      float4 lo = fp[2 * id], hi = fp[2 * id + 1];
      f.u[0] = f2bf(lo.x); f.u[1] = f2bf(lo.y); f.u[2] = f2bf(lo.z); f.u[3] = f2bf(lo.w);
      f.u[4] = f2bf(hi.x); f.u[5] = f2bf(hi.y); f.u[6] = f2bf(hi.z); f.u[7] = f2bf(hi.w);
    }
    return f;
  };

  // ---- weight fragments (once per block) ----
  const void* Wup[3] = {Wfu, Wgu, Wcu};
  const int gate = w >> 2;
  const int colg = ((w & 3) * 16) + l15;
  FragU wfrag[6];
#pragma unroll
  for (int kc = 0; kc < 6; ++kc) {
#pragma unroll
    for (int j = 0; j < 8; ++j) {
      int r = kc * 32 + quad * 8 + j;
      wfrag[kc].u[j] = ldbf(Wup[gate], (r >> 6) * 4096 + (r & 63) * 64 + colg);
    }
  }
  FragU efrag[4];
#pragma unroll
  for (int kc = 0; kc < 4; ++kc) {
#pragma unroll
    for (int j = 0; j < 8; ++j) {
      int c = kc * 32 + quad * 8 + j;
      efrag[kc].u[j] = ldbf(encW, c * 64 + ((w & 3) * 16 + l15));
    }
  }
  if (tid < 64) sh_encB[tid] = ldf(encb, tid);

  auto tile64 = [&](const u16* A, const u16* BT, u16* C, int mt, int nt) {
    f32x4 acc = {0.f, 0.f, 0.f, 0.f};
    bf16x8 a0 = *(const bf16x8*)(A  + (mt * 16 + l15) * ST + quad * 8);
    bf16x8 b0 = *(const bf16x8*)(BT + (nt * 16 + l15) * ST + quad * 8);
    acc = __builtin_amdgcn_mfma_f32_16x16x32_bf16(a0, b0, acc, 0, 0, 0);
    bf16x8 a1 = *(const bf16x8*)(A  + (mt * 16 + l15) * ST + 32 + quad * 8);
    bf16x8 b1 = *(const bf16x8*)(BT + (nt * 16 + l15) * ST + 32 + quad * 8);
    acc = __builtin_amdgcn_mfma_f32_16x16x32_bf16(a1, b1, acc, 0, 0, 0);
    int cb = (mt * 16 + quad * 4) * ST + nt * 16 + l15;
    C[cb]          = f2bf(acc[0]);
    C[cb + ST]     = f2bf(acc[1]);
    C[cb + 2 * ST] = f2bf(acc[2]);
    C[cb + 3 * ST] = f2bf(acc[3]);
  };
  auto encTile = [&](int mt, int dt) {
    f32x4 acc = {0.f, 0.f, 0.f, 0.f};
#pragma unroll
    for (int kc = 0; kc < 4; ++kc) {
      bf16x8 a = *(const bf16x8*)(sh_fT + (mt * 16 + l15) * FST + kc * 32 + quad * 8);
      acc = __builtin_amdgcn_mfma_f32_16x16x32_bf16(a, efrag[kc].v, acc, 0, 0, 0);
    }
    int d = dt * 16 + l15;
    float eb = sh_encB[d];
#pragma unroll
    for (int r = 0; r < 4; ++r) {
      int n = mt * 16 + quad * 4 + r;
      u16 hv = f2bf(acc[r] + eb);
      sh_xt[n * ST + d]  = hv;
      sh_xtT[d * ST + n] = hv;
    }
  };

  f32x4 gacc[4];
  auto gstep = [&](const u16* buf, int koff, const FragU& wf) {
#pragma unroll
    for (int mt = 0; mt < 4; ++mt) {
      bf16x8 a = *(const bf16x8*)(buf + (mt * 16 + l15) * ST + koff + quad * 8);
      gacc[mt] = __builtin_amdgcn_mfma_f32_16x16x32_bf16(a, wf.v, gacc[mt], 0, 0, 0);
    }
  };

  for (int rec = rec0; rec < 1024; rec += recStride) {
    const int b = rec >> 4;
    const int t = t0 + (rec & 15);
    __syncthreads();   // previous iteration's readers done before restaging

    // ---- stage At + At^T + featsT ----
    {
      const void* ag = isf32 ? (const void*)((const float*)adj + (size_t)(b * 128 + t) * 4096)
                             : (const void*)((const u16*)adj + (size_t)(b * 128 + t) * 4096);
      const void* fg = isf32 ? (const void*)((const float*)frames + (size_t)(b * 128 + t) * 8192)
                             : (const void*)((const u16*)frames + (size_t)(b * 128 + t) * 8192);
      for (int id = tid; id < 1536; id += 768) {
        if (id < 512) {
          FragU f = fetch8(ag, id);
          int r = id >> 3, c8 = (id & 7) * 8;
          *(uint4*)(sh_At + r * ST + c8) = f.q;
#pragma unroll
          for (int j = 0; j < 8; ++j) sh_AtT[(c8 + j) * ST + r] = f.u[j];
        } else {
          int k = id - 512;
          FragU f = fetch8(fg, k);
          int c = k >> 3, n8 = (k & 7) * 8;
#pragma unroll
          for (int j = 0; j < 8; ++j) sh_fT[(n8 + j) * FST + c] = f.u[j];
        }
      }
    }
    __syncthreads();

    // ---- Phase B: encoder + S2 ----
    encTile(w >> 2, w & 3);
    if (w < 4) encTile(3, w);
    tile64(sh_At, sh_AtT, sh_S2, w >> 2, w & 3);
    if (w < 4) tile64(sh_At, sh_AtT, sh_S2, 3, w);
    __syncthreads();

    // ---- Phase C: yx1 = At@xt, yx2 = S2@xt ; dump S2 -> ws ----
#pragma unroll
    for (int i = 0; i < 3; ++i) {
      int id = w + 12 * i;
      if (id < 16)      tile64(sh_At, sh_xtT, sh_Y1, id >> 2, id & 3);
      else if (id < 32) tile64(sh_S2, sh_xtT, sh_Y2, (id - 16) >> 2, (id - 16) & 3);
    }
    {
      uint4* s2o = (uint4*)(ws + s2_base + (size_t)rec * 9216);
      for (int id = tid; id < 576; id += 768) s2o[id] = ((const uint4*)sh_S2)[id];
    }
    __syncthreads();

    // ---- Phase D: gu = [xt,yx1,yx2] @ W_u -> ws ----
    {
      f32x4 z = {0.f, 0.f, 0.f, 0.f};
      gacc[0] = z; gacc[1] = z; gacc[2] = z; gacc[3] = z;
    }
    gstep(sh_xt, 0, wfrag[0]); gstep(sh_xt, 32, wfrag[1]);
    gstep(sh_Y1, 0, wfrag[2]); gstep(sh_Y1, 32, wfrag[3]);
    gstep(sh_Y2, 0, wfrag[4]); gstep(sh_Y2, 32, wfrag[5]);
    {
      float* gp = (float*)(ws + gu_base + (size_t)rec * 49152) + tid * 16;
      *(f32x4*)(gp + 0)  = gacc[0];
      *(f32x4*)(gp + 4)  = gacc[1];
      *(f32x4*)(gp + 8)  = gacc[2];
      *(f32x4*)(gp + 12) = gacc[3];
    }
  }
}

// ============================================================================
// SEQ body: recurrence over CH timesteps for batch b (verified round-3 logic,
// parametrized by ws bases).
// ============================================================================
__device__ void seq_body(
    const void* __restrict__ frames, const void* __restrict__ adj, const void* __restrict__ hid0,
    const void* __restrict__ Wfh, const void* __restrict__ Wgh, const void* __restrict__ Wch,
    const void* __restrict__ bfp, const void* __restrict__ bgp, const void* __restrict__ bcp,
    const void* __restrict__ dW1, const void* __restrict__ db1,
    const void* __restrict__ dW2, const void* __restrict__ db2,
    const void* __restrict__ dW3, const void* __restrict__ db3,
    const void* __restrict__ osc, const void* __restrict__ obi,
    void* __restrict__ outv, char* __restrict__ ws, u64 s2_base, u64 gu_base,
    int t0, int b,
    u16* lds, float* F, int* sh_flag)
{
  u16* sh_h   = lds;            // 4608
  u16* sh_hT  = lds + 4608;
  u16* sh_Y1  = lds + 9216;
  u16* sh_Y2  = lds + 13824;
  u16* sh_G   = lds + 18432;    // 3*4608
  u16* sh_buf = lds + 32256;    // At 4608 + S2 4608 (single buffer)
  float* sh_dW1   = F;          // 8192
  float* sh_dW2   = F + 8192;   // 8192
  float* sh_dW3   = F + 16384;  // 384
  float* sh_biasG = F + 16768;  // 192
  float* sh_pooled= F + 16960;  // 64
  float* sh_z1    = F + 17024;  // 128
  float* sh_z2    = F + 17152;  // 64
  float* sh_db1   = F + 17216;  // 128
  float* sh_db2   = F + 17344;  // 64
  float* sh_db3   = F + 17408;  // 8
  float* sh_osc   = F + 17416;  // 8
  float* sh_obi   = F + 17424;  // 8

  const int tid  = threadIdx.x;
  const int w    = tid >> 6;
  const int lane = tid & 63;
  const int quad = lane >> 4;
  const int l15  = lane & 15;

  const bool isf32 = detect_f32(frames, sh_flag);

  auto ldbf = [&](const void* p, int i) -> u16 {
    return isf32 ? f2bf(((const float*)p)[i]) : ((const u16*)p)[i];
  };
  auto ldf = [&](const void* p, int i) -> float {
    return isf32 ? ((const float*)p)[i] : bf2f(((const u16*)p)[i]);
  };
  auto fetch8 = [&](const void* p, int id) -> FragU {
    FragU f;
    if (!isf32) {
      f.q = ((const uint4*)p)[id];
    } else {
      const float4* fp = (const float4*)p;
      float4 lo = fp[2 * id], hi = fp[2 * id + 1];
      f.u[0] = f2bf(lo.x); f.u[1] = f2bf(lo.y); f.u[2] = f2bf(lo.z); f.u[3] = f2bf(lo.w);
      f.u[4] = f2bf(hi.x); f.u[5] = f2bf(hi.y); f.u[6] = f2bf(hi.z); f.u[7] = f2bf(hi.w);
    }
    return f;
  };
  auto stout = [&](int i, float v) {
    if (isf32) ((float*)outv)[i] = v; else ((u16*)outv)[i] = f2bf(v);
  };

  // ---- W_h fragments ----
  const void* Whp[3] = {Wfh, Wgh, Wch};
  const int gate = w >> 2;
  const int colg = ((w & 3) * 16) + l15;
  FragU wfrag[6];
#pragma unroll
  for (int kc = 0; kc < 6; ++kc) {
#pragma unroll
    for (int j = 0; j < 8; ++j) {
      int r = kc * 32 + quad * 8 + j;
      wfrag[kc].u[j] = ldbf(Whp[gate], (r >> 6) * 4096 + (r & 63) * 64 + colg);
    }
  }
  if (tid < 192) {
    const void* bp = (tid < 64) ? bfp : (tid < 128 ? bgp : bcp);
    sh_biasG[tid] = ldf(bp, tid & 63);
  }

  // ---- one-time decoder weight staging (f32, value-identical) ----
  for (int i = tid; i < 8192; i += 768) sh_dW1[i] = ldf(dW1, i);
  for (int i = tid; i < 8192; i += 768) sh_dW2[i] = ldf(dW2, i);
  if (tid < 384) sh_dW3[tid] = ldf(dW3, tid);
  if (tid < 128) sh_db1[tid] = ldf(db1, tid);
  if (tid < 64)  sh_db2[tid] = ldf(db2, tid);
  if (tid < 6) {
    sh_db3[tid] = ldf(db3, tid);
    sh_osc[tid] = ldf(osc, tid);
    sh_obi[tid] = ldf(obi, tid);
  }

  u16* wsh = (u16*)ws;   // h carry (bf16)

  // ---- stage h ----
  for (int st = tid; st < 512; st += 768) {
    FragU f;
    if (t0 == 0) {
      const void* hg = isf32 ? (const void*)((const float*)hid0 + (size_t)b * 4096)
                             : (const void*)((const u16*)hid0 + (size_t)b * 4096);
      f = fetch8(hg, st);
    } else {
      f.q = ((const uint4*)(wsh + (size_t)b * 4096))[st];
    }
    int n = st >> 3, d8 = (st & 7) * 8;
    *(uint4*)(sh_h + n * ST + d8) = f.q;
#pragma unroll
    for (int j = 0; j < 8; ++j) sh_hT[(d8 + j) * ST + n] = f.u[j];
  }

  auto tile64 = [&](const u16* A, const u16* BT, u16* C, int mt, int nt) {
    f32x4 acc = {0.f, 0.f, 0.f, 0.f};
    bf16x8 a0 = *(const bf16x8*)(A  + (mt * 16 + l15) * ST + quad * 8);
    bf16x8 b0 = *(const bf16x8*)(BT + (nt * 16 + l15) * ST + quad * 8);
    acc = __builtin_amdgcn_mfma_f32_16x16x32_bf16(a0, b0, acc, 0, 0, 0);
    bf16x8 a1 = *(const bf16x8*)(A  + (mt * 16 + l15) * ST + 32 + quad * 8);
    bf16x8 b1 = *(const bf16x8*)(BT + (nt * 16 + l15) * ST + 32 + quad * 8);
    acc = __builtin_amdgcn_mfma_f32_16x16x32_bf16(a1, b1, acc, 0, 0, 0);
    int cb = (mt * 16 + quad * 4) * ST + nt * 16 + l15;
    C[cb]          = f2bf(acc[0]);
    C[cb + ST]     = f2bf(acc[1]);
    C[cb + 2 * ST] = f2bf(acc[2]);
    C[cb + 3 * ST] = f2bf(acc[3]);
  };

  f32x4 gacc[4];
  auto gstep = [&](const u16* buf, int koff, const FragU& wf) {
#pragma unroll
    for (int mt = 0; mt < 4; ++mt) {
      bf16x8 a = *(const bf16x8*)(buf + (mt * 16 + l15) * ST + koff + quad * 8);
      gacc[mt] = __builtin_amdgcn_mfma_f32_16x16x32_bf16(a, wf.v, gacc[mt], 0, 0, 0);
    }
  };

  auto stageSeq = [&](int tn, int tln, int st0, int stride) {
    u16* dAt = sh_buf;
    u16* dS2 = dAt + 4608;
    const void* ag = isf32 ? (const void*)((const float*)adj + (size_t)(b * 128 + tn) * 4096)
                           : (const void*)((const u16*)adj + (size_t)(b * 128 + tn) * 4096);
    const uint4* s2g = (const uint4*)(ws + s2_base + (size_t)((b << 4) + tln) * 9216);
    for (int id = st0; id < 1088; id += stride) {
      if (id < 512) {
        FragU f = fetch8(ag, id);
        int r = id >> 3, c8 = (id & 7) * 8;
        *(uint4*)(dAt + r * ST + c8) = f.q;
      } else {
        ((uint4*)dS2)[id - 512] = s2g[id - 512];
      }
    }
  };

  const float* gub = (const float*)(ws + gu_base);
  Pf pA, pB;
  stageSeq(t0, 0, tid, 768);
  {
    const float* gp = gub + (size_t)(b << 4) * 12288 + tid * 16;
    pA.a = *(const f32x4*)(gp);     pA.b = *(const f32x4*)(gp + 4);
    pA.c = *(const f32x4*)(gp + 8); pA.d = *(const f32x4*)(gp + 12);
  }
  __syncthreads();

  auto step = [&](int t, int tl, Pf& use, Pf& nxt) {
    u16* At  = sh_buf;
    u16* S2v = At + 4608;

    // ---- Phase E ----
    gacc[0] = use.a; gacc[1] = use.b; gacc[2] = use.c; gacc[3] = use.d;
    gstep(sh_h, 0, wfrag[0]); gstep(sh_h, 32, wfrag[1]);
#pragma unroll
    for (int i = 0; i < 3; ++i) {
      int id = w + 12 * i;
      if (id < 16)      tile64(At,  sh_hT, sh_Y1, id >> 2, id & 3);
      else if (id < 32) tile64(S2v, sh_hT, sh_Y2, (id - 16) >> 2, (id - 16) & 3);
    }
    __syncthreads();

    // ---- Phase F ----
    gstep(sh_Y1, 0, wfrag[2]); gstep(sh_Y1, 32, wfrag[3]);
    gstep(sh_Y2, 0, wfrag[4]); gstep(sh_Y2, 32, wfrag[5]);
    {
      float bias = sh_biasG[w * 16 + l15];
      u16* G = sh_G + gate * 4608;
      int col = (w & 3) * 16 + l15;
#pragma unroll
      for (int mt = 0; mt < 4; ++mt) {
#pragma unroll
        for (int r = 0; r < 4; ++r)
          G[(mt * 16 + quad * 4 + r) * ST + col] = f2bf(gacc[mt][r] + bias);
      }
    }
    if (tid < 64) sh_pooled[tid] = 0.f;
    __syncthreads();

    // ---- Phase G ----
    {
      float psum = 0.f;
      int d = tid & 63;
#pragma unroll
      for (int i = 0; i < 6; ++i) {
        int idx = tid + i * 768;
        if (idx < 4096) {
          int n = idx >> 6;
          float ff = bf2f(sh_G[n * ST + d]);
          float gg = bf2f(sh_G[4608 + n * ST + d]);
          float cc = bf2f(sh_G[9216 + n * ST + d]);
          float sig = 1.f / (1.f + __expf(-ff));
          float tg = 1.f - 2.f / (__expf(2.f * gg) + 1.f);
          float tc = 1.f - 2.f / (__expf(2.f * cc) + 1.f);
          float hn = sig * tg + (1.f - sig) * tc;
          u16 hv = f2bf(hn);
          sh_h[n * ST + d]  = hv;
          sh_hT[d * ST + n] = hv;
          psum += hn;
          if (t == 127) stout(49152 + (b << 12) + idx, hn);     // final_hidden
          if (tl == 15) wsh[(size_t)b * 4096 + idx] = hv;       // h carry
        }
      }
      atomicAdd(&sh_pooled[d], psum);
    }
    __syncthreads();

    // ---- Phase H ----
    if (tl < 15) {
      const float* gp = gub + (size_t)((b << 4) + tl + 1) * 12288 + tid * 16;
      nxt.a = *(const f32x4*)(gp);     nxt.b = *(const f32x4*)(gp + 4);
      nxt.c = *(const f32x4*)(gp + 8); nxt.d = *(const f32x4*)(gp + 12);
    }
    if (w == 0) {
      int l = tid;
      float p = sh_pooled[l] * (1.f / 64.f);
      sh_pooled[l] = p;   // same-wave write->read ordering
      float a0 = sh_db1[l], a1 = sh_db1[l + 64];
      float c0 = 0.f, c1 = 0.f;
#pragma unroll 8
      for (int c = 0; c < 64; c += 2) {
        float p0 = sh_pooled[c], p1 = sh_pooled[c + 1];
        a0 += p0 * sh_dW1[c * 128 + l];
        a1 += p0 * sh_dW1[c * 128 + 64 + l];
        c0 += p1 * sh_dW1[(c + 1) * 128 + l];
        c1 += p1 * sh_dW1[(c + 1) * 128 + 64 + l];
      }
      sh_z1[l]      = fmaxf(a0 + c0, 0.f);
      sh_z1[l + 64] = fmaxf(a1 + c1, 0.f);
      float s0 = sh_db2[l], s1 = 0.f, s2 = 0.f, s3 = 0.f;
#pragma unroll 8
      for (int c = 0; c < 128; c += 4) {
        s0 += sh_z1[c]     * sh_dW2[c * 64 + l];
        s1 += sh_z1[c + 1] * sh_dW2[(c + 1) * 64 + l];
        s2 += sh_z1[c + 2] * sh_dW2[(c + 2) * 64 + l];
        s3 += sh_z1[c + 3] * sh_dW2[(c + 3) * 64 + l];
      }
      sh_z2[l] = fmaxf(s0 + s1 + s2 + s3, 0.f);
      if (l < 6) {
        float acc = sh_db3[l];
#pragma unroll 8
        for (int c = 0; c < 64; ++c) acc += sh_z2[c] * sh_dW3[c * 6 + l];
        float val = acc * sh_osc[l] + sh_obi[l];
        stout((b * 128 + t) * 6 + l, val);   // controls
      }
    } else if (tl < 15) {
      stageSeq(t + 1, tl + 1, tid - 64, 704);
    }
    __syncthreads();
  };

#pragma unroll 1
  for (int tl = 0; tl < CH; tl += 2) {
    step(t0 + tl,     tl,     pA, pB);
    step(t0 + tl + 1, tl + 1, pB, pA);
  }
}

// ============================================================================
// Fused kernel: blocks [0,nseq) run seq; blocks [nseq,grid) run pre.
// nseq = do_seq ? 64 : 0. Bases passed explicitly -> serves both ws layouts.
// ============================================================================
__global__ __launch_bounds__(768, 1) void cfgcn_fused(
    const void* __restrict__ frames, const void* __restrict__ adj, const void* __restrict__ hid0,
    const void* __restrict__ encW, const void* __restrict__ encb,
    const void* __restrict__ Wfh, const void* __restrict__ Wfu, const void* __restrict__ bfp,
    const void* __restrict__ Wgh, const void* __restrict__ Wgu, const void* __restrict__ bgp,
    const void* __restrict__ Wch, const void* __restrict__ Wcu, const void* __restrict__ bcp,
    const void* __restrict__ dW1, const void* __restrict__ db1,
    const void* __restrict__ dW2, const void* __restrict__ db2,
    const void* __restrict__ dW3, const void* __restrict__ db3,
    const void* __restrict__ osc, const void* __restrict__ obi,
    void* __restrict__ outv, char* __restrict__ ws,
    int do_seq, int t0seq, u64 s2_seq, u64 gu_seq,
    int do_pre, int t0pre, u64 s2_pre, u64 gu_pre)
{
  __shared__ alignas(16) char smem[152688];
  const int nseq = do_seq ? 64 : 0;
  if ((int)blockIdx.x < nseq) {
    u16* lds  = (u16*)smem;                       // 82944 B tiles
    float* F  = (float*)(smem + 82944);           // 17432 floats
    int* flag = (int*)(smem + 152672);
    seq_body(frames, adj, hid0, Wfh, Wgh, Wch, bfp, bgp, bcp,
             dW1, db1, dW2, db2, dW3, db3, osc, obi,
             outv, ws, s2_seq, gu_seq, t0seq, (int)blockIdx.x, lds, F, flag);
  } else if (do_pre) {
    u16* plds   = (u16*)smem;                     // 64512 B tiles
    float* encB = (float*)(smem + 64512);
    int* flag   = (int*)(smem + 64768);
    pre_body(frames, adj, encW, encb, Wfu, Wgu, Wcu,
             ws, s2_pre, gu_pre, t0pre,
             (int)blockIdx.x - nseq, (int)gridDim.x - nseq, plds, encB, flag);
  }
}

// ============================================================================
// Fallback: the verified monolithic kernel (workspace too small)
// ============================================================================
__global__ __launch_bounds__(768, 1) void cfgcn(
    const void* __restrict__ frames, const void* __restrict__ adj,
    const void* __restrict__ hid0, const void* __restrict__ encW, const void* __restrict__ encb,
    const void* __restrict__ Wfh, const void* __restrict__ Wfu, const void* __restrict__ bfp,
    const void* __restrict__ Wgh, const void* __restrict__ Wgu, const void* __restrict__ bgp,
    const void* __restrict__ Wch, const void* __restrict__ Wcu, const void* __restrict__ bcp,
    const void* __restrict__ dW1, const void* __restrict__ db1,
    const void* __restrict__ dW2, const void* __restrict__ db2,
    const void* __restrict__ dW3, const void* __restrict__ db3,
    const void* __restrict__ osc, const void* __restrict__ obi,
    void* __restrict__ outv)
{
  __shared__ alignas(16) u16 lds[64000];
  u16* sh_h   = lds +     0;
  u16* sh_hT  = lds +  4608;
  u16* sh_At  = lds +  9216;
  u16* sh_AtT = lds + 13824;
  u16* sh_S2  = lds + 18432;
  u16* sh_xt  = lds + 23040;
  u16* sh_xtT = lds + 27648;
  u16* sh_Y1  = lds + 32256;
  u16* sh_Y2  = lds + 36864;
  u16* sh_G   = lds + 41472;
  u16* sh_fT  = lds + 55296;
  __shared__ float sh_biasG[192], sh_encB[64], sh_pooled[64], sh_z1[128], sh_z2[64];
  __shared__ int sh_flag;

  const int b    = blockIdx.x;
  const int tid  = threadIdx.x;
  const int w    = tid >> 6;
  const int lane = tid & 63;
  const int quad = lane >> 4;
  const int l15  = lane & 15;

  if (tid == 0) sh_flag = 0;
  for (int i = tid; i < 64000; i += 768) lds[i] = 0;
  __syncthreads();
  {
    int c = 0;
    const u16* fu = (const u16*)frames;
    for (int i = tid; i < 8192; i += 768) {
      u16 u = fu[i];
      c += ((u & 0x7F80u) >= 0x6000u) ? 1 : 0;
    }
    if (c) atomicAdd(&sh_flag, c);
  }
  __syncthreads();
  const bool isf32 = (sh_flag > 16);

  auto ldbf = [&](const void* p, int i) -> u16 {
    return isf32 ? f2bf(((const float*)p)[i]) : ((const u16*)p)[i];
  };
  auto ldf = [&](const void* p, int i) -> float {
    return isf32 ? ((const float*)p)[i] : bf2f(((const u16*)p)[i]);
  };
  auto fetch8 = [&](const void* p, int id) -> FragU {
    FragU f;
    if (!isf32) {
      f.q = ((const uint4*)p)[id];
    } else {
      const float4* fp = (const float4*)p;
      float4 lo = fp[2 * id], hi = fp[2 * id + 1];
      f.u[0] = f2bf(lo.x); f.u[1] = f2bf(lo.y); f.u[2] = f2bf(lo.z); f.u[3] = f2bf(lo.w);
      f.u[4] = f2bf(hi.x); f.u[5] = f2bf(hi.y); f.u[6] = f2bf(hi.z); f.u[7] = f2bf(hi.w);
    }
    return f;
  };
  auto stout = [&](int i, float v) {
    if (isf32) ((float*)outv)[i] = v; else ((u16*)outv)[i] = f2bf(v);
  };

  const void* Whp[3] = {Wfh, Wgh, Wch};
  const void* Wup[3] = {Wfu, Wgu, Wcu};
  const int gate = w >> 2;
  const int colg = ((w & 3) * 16) + l15;
  FragU wfrag[12];
#pragma unroll
  for (int kc = 0; kc < 12; ++kc) {
#pragma unroll
    for (int j = 0; j < 8; ++j) {
      int r = kc * 32 + quad * 8 + j;
      const void* src = (r < 192) ? Whp[gate] : Wup[gate];
      int rr = (r < 192) ? r : r - 192;
      wfrag[kc].u[j] = ldbf(src, (rr >> 6) * 4096 + (rr & 63) * 64 + colg);
    }
  }
  FragU efrag[4];
#pragma unroll
  for (int kc = 0; kc < 4; ++kc) {
#pragma unroll
    for (int j = 0; j < 8; ++j) {
      int c = kc * 32 + quad * 8 + j;
      efrag[kc].u[j] = ldbf(encW, c * 64 + ((w & 3) * 16 + l15));
    }
  }
  if (tid < 192) {
    const void* bp = (tid < 64) ? bfp : (tid < 128 ? bgp : bcp);
    sh_biasG[tid] = ldf(bp, tid & 63);
  }
  if (tid < 64) sh_encB[tid] = ldf(encb, tid);

  {
    const void* hg = isf32 ? (const void*)((const float*)hid0 + (size_t)b * 4096)
                           : (const void*)((const u16*)hid0 + (size_t)b * 4096);
    for (int st = tid; st < 512; st += 768) {
      FragU f = fetch8(hg, st);
      int n = st >> 3, d8 = (st & 7) * 8;
      *(uint4*)(sh_h + n * ST + d8) = f.q;
#pragma unroll
      for (int j = 0; j < 8; ++j) sh_hT[(d8 + j) * ST + n] = f.u[j];
    }
  }

  auto stage = [&](int tt, int st0, int stride) {
    const void* ag = isf32 ? (const void*)((const float*)adj + (size_t)(b * 128 + tt) * 4096)
                           : (const void*)((const u16*)adj + (size_t)(b * 128 + tt) * 4096);
    const void* fg = isf32 ? (const void*)((const float*)frames + (size_t)(b * 128 + tt) * 8192)
                           : (const void*)((const u16*)frames + (size_t)(b * 128 + tt) * 8192);
    for (int id = st0; id < 1536; id += stride) {
      if (id < 512) {
        FragU f = fetch8(ag, id);
        int r = id >> 3, c8 = (id & 7) * 8;
        *(uint4*)(sh_At + r * ST + c8) = f.q;
#pragma unroll
        for (int j = 0; j < 8; ++j) sh_AtT[(c8 + j) * ST + r] = f.u[j];
      } else {
        int k = id - 512;
        FragU f = fetch8(fg, k);
        int c = k >> 3, n8 = (k & 7) * 8;
#pragma unroll
        for (int j = 0; j < 8; ++j) sh_fT[(n8 + j) * FST + c] = f.u[j];
      }
    }
  };
  stage(0, tid, 768);

  auto tile64 = [&](const u16* A, const u16* BT, u16* C, int mt, int nt) {
    f32x4 acc = {0.f, 0.f, 0.f, 0.f};
    bf16x8 a0 = *(const bf16x8*)(A  + (mt * 16 + l15) * ST + quad * 8);
    bf16x8 b0 = *(const bf16x8*)(BT + (nt * 16 + l15) * ST + quad * 8);
    acc = __builtin_amdgcn_mfma_f32_16x16x32_bf16(a0, b0, acc, 0, 0, 0);
    bf16x8 a1 = *(const bf16x8*)(A  + (mt * 16 + l15) * ST + 32 + quad * 8);
    bf16x8 b1 = *(const bf16x8*)(BT + (nt * 16 + l15) * ST + 32 + quad * 8);
    acc = __builtin_amdgcn_mfma_f32_16x16x32_bf16(a1, b1, acc, 0, 0, 0);
    int cb = (mt * 16 + quad * 4) * ST + nt * 16 + l15;
    C[cb]          = f2bf(acc[0]);
    C[cb + ST]     = f2bf(acc[1]);
    C[cb + 2 * ST] = f2bf(acc[2]);
    C[cb + 3 * ST] = f2bf(acc[3]);
  };

  auto encTile = [&](int mt, int dt) {
    f32x4 acc = {0.f, 0.f, 0.f, 0.f};
#pragma unroll
    for (int kc = 0; kc < 4; ++kc) {
      bf16x8 a = *(const bf16x8*)(sh_fT + (mt * 16 + l15) * FST + kc * 32 + quad * 8);
      acc = __builtin_amdgcn_mfma_f32_16x16x32_bf16(a, efrag[kc].v, acc, 0, 0, 0);
    }
    int d = dt * 16 + l15;
    float eb = sh_encB[d];
#pragma unroll
    for (int r = 0; r < 4; ++r) {
      int n = mt * 16 + quad * 4 + r;
      u16 hv = f2bf(acc[r] + eb);
      sh_xt[n * ST + d]  = hv;
      sh_xtT[d * ST + n] = hv;
    }
  };

  f32x4 gacc[4];
  auto gstep = [&](const u16* buf, int koff, const FragU& wf) {
#pragma unroll
    for (int mt = 0; mt < 4; ++mt) {
      bf16x8 a = *(const bf16x8*)(buf + (mt * 16 + l15) * ST + koff + quad * 8);
      gacc[mt] = __builtin_amdgcn_mfma_f32_16x16x32_bf16(a, wf.v, gacc[mt], 0, 0, 0);
    }
  };

  __syncthreads();

  for (int t = 0; t < 128; ++t) {
    encTile(w >> 2, w & 3);
    if (w < 4) encTile(3, w);
    tile64(sh_At, sh_AtT, sh_S2, w >> 2, w & 3);
    if (w < 4) tile64(sh_At, sh_AtT, sh_S2, 3, w);
    __syncthreads();

#pragma unroll
    for (int i = 0; i < 3; ++i) {
      int id = w + 12 * i;
      if (id < 16)      tile64(sh_At, sh_xtT, sh_Y1, id >> 2, id & 3);
      else if (id < 32) tile64(sh_S2, sh_xtT, sh_Y2, (id - 16) >> 2, (id - 16) & 3);
    }
    __syncthreads();

    {
      f32x4 z = {0.f, 0.f, 0.f, 0.f};
      gacc[0] = z; gacc[1] = z; gacc[2] = z; gacc[3] = z;
    }
    gstep(sh_xt, 0, wfrag[6]);  gstep(sh_xt, 32, wfrag[7]);
    gstep(sh_Y1, 0, wfrag[8]);  gstep(sh_Y1, 32, wfrag[9]);
    gstep(sh_Y2, 0, wfrag[10]); gstep(sh_Y2, 32, wfrag[11]);
    __syncthreads();

#pragma unroll
    for (int i = 0; i < 3; ++i) {
      int id = w + 12 * i;
      if (id < 16)      tile64(sh_At, sh_hT, sh_Y1, id >> 2, id & 3);
      else if (id < 32) tile64(sh_S2, sh_hT, sh_Y2, (id - 16) >> 2, (id - 16) & 3);
    }
    __syncthreads();

    gstep(sh_h,  0, wfrag[0]); gstep(sh_h,  32, wfrag[1]);
    gstep(sh_Y1, 0, wfrag[2]); gstep(sh_Y1, 32, wfrag[3]);
    gstep(sh_Y2, 0, wfrag[4]); gstep(sh_Y2, 32, wfrag[5]);
    {
      float bias = sh_biasG[w * 16 + l15];
      u16* G = sh_G + gate * 4608;
      int col = (w & 3) * 16 + l15;
#pragma unroll
      for (int mt = 0; mt < 4; ++mt) {
#pragma unroll
        for (int r = 0; r < 4; ++r)
          G[(mt * 16 + quad * 4 + r) * ST + col] = f2bf(gacc[mt][r] + bias);
      }
    }
    if (tid < 64) sh_pooled[tid] = 0.f;
    __syncthreads();

    {
      float psum = 0.f;
      int d = tid & 63;
#pragma unroll
      for (int i = 0; i < 6; ++i) {
        int idx = tid + i * 768;
        if (idx < 4096) {
          int n = idx >> 6;
          float ff = bf2f(sh_G[n * ST + d]);
          float gg = bf2f(sh_G[4608 + n * ST + d]);
          float cc = bf2f(sh_G[9216 + n * ST + d]);
          float sig = 1.f / (1.f + __expf(-ff));
          float tg = 1.f - 2.f / (__expf(2.f * gg) + 1.f);
          float tc = 1.f - 2.f / (__expf(2.f * cc) + 1.f);
          float hn = sig * tg + (1.f - sig) * tc;
          u16 hv = f2bf(hn);
          sh_h[n * ST + d]  = hv;
          sh_hT[d * ST + n] = hv;
          psum += hn;
          if (t == 127) stout(49152 + (b << 12) + idx, hn);
        }
      }
      atomicAdd(&sh_pooled[d], psum);
    }
    __syncthreads();

    if (w == 0) {
      int l = tid;
      float p = sh_pooled[l] * (1.f / 64.f);
      sh_pooled[l] = p;
      float a0 = ldf(db1, l), a1 = ldf(db1, l + 64);
      float c0 = 0.f, c1 = 0.f;
#pragma unroll 8
      for (int c = 0; c < 64; c += 2) {
        float p0 = sh_pooled[c], p1 = sh_pooled[c + 1];
        a0 += p0 * ldf(dW1, c * 128 + l);
        a1 += p0 * ldf(dW1, c * 128 + 64 + l);
        c0 += p1 * ldf(dW1, (c + 1) * 128 + l);
        c1 += p1 * ldf(dW1, (c + 1) * 128 + 64 + l);
      }
      sh_z1[l]      = fmaxf(a0 + c0, 0.f);
      sh_z1[l + 64] = fmaxf(a1 + c1, 0.f);
      float s0 = ldf(db2, l), s1 = 0.f, s2 = 0.f, s3 = 0.f;
#pragma unroll 8
      for (int c = 0; c < 128; c += 4) {
        s0 += sh_z1[c]     * ldf(dW2, c * 64 + l);
        s1 += sh_z1[c + 1] * ldf(dW2, (c + 1) * 64 + l);
        s2 += sh_z1[c + 2] * ldf(dW2, (c + 2) * 64 + l);
        s3 += sh_z1[c + 3] * ldf(dW2, (c + 3) * 64 + l);
      }
      sh_z2[l] = fmaxf(s0 + s1 + s2 + s3, 0.f);
      if (l < 6) {
        float acc = ldf(db3, l);
#pragma unroll 8
        for (int c = 0; c < 64; ++c) acc += sh_z2[c] * ldf(dW3, c * 6 + l);
        float val = acc * ldf(osc, l) + ldf(obi, l);
        stout((b * 128 + t) * 6 + l, val);
      }
    } else if (t < 127) {
      stage(t + 1, tid - 64, 768 - 64);
    }
    __syncthreads();
  }
}

extern "C" void kernel_launch(void* const* d_in, const int* in_sizes, int n_in,
                              void* d_out, int out_size, void* d_ws, size_t ws_size,
                              hipStream_t stream) {
  (void)in_sizes; (void)n_in; (void)out_size;
  if (d_ws && ws_size >= (size_t)WS_NEED_PIPE) {
    // ---- path A: pipelined {seq(c) || pre(c+1)} ----
    auto s2s = [](int s) -> u64 { return (u64)P_S2_OFF + (u64)s * P_S2_SLOT; };
    auto gus = [](int s) -> u64 { return (u64)P_GU_OFF + (u64)s * P_GU_SLOT; };
    cfgcn_fused<<<dim3(256), dim3(768), 0, stream>>>(
        d_in[0], d_in[1], d_in[2], d_in[3], d_in[4], d_in[5], d_in[6], d_in[7],
        d_in[8], d_in[9], d_in[10], d_in[11], d_in[12], d_in[13], d_in[14], d_in[15],
        d_in[16], d_in[17], d_in[18], d_in[19], d_in[20], d_in[21], d_out,
        (char*)d_ws, 0, 0, 0ull, 0ull, 1, 0, s2s(0), gus(0));
    for (int c = 0; c < 8; ++c) {
      const int doPre = (c < 7) ? 1 : 0;
      dim3 grid(doPre ? 256 : 64);
      cfgcn_fused<<<grid, dim3(768), 0, stream>>>(
          d_in[0], d_in[1], d_in[2], d_in[3], d_in[4], d_in[5], d_in[6], d_in[7],
          d_in[8], d_in[9], d_in[10], d_in[11], d_in[12], d_in[13], d_in[14], d_in[15],
          d_in[16], d_in[17], d_in[18], d_in[19], d_in[20], d_in[21], d_out,
          (char*)d_ws, 1, c * CH, s2s(c & 1), gus(c & 1),
          doPre, (c + 1) * CH, s2s((c + 1) & 1), gus((c + 1) & 1));
    }
  } else if (d_ws && ws_size >= (size_t)WS_NEED) {
    // ---- path B: serialized chunks via the same fused kernel ----
    for (int c = 0; c < 8; ++c) {
      const int t0 = c * CH;
      cfgcn_fused<<<dim3(256), dim3(768), 0, stream>>>(
          d_in[0], d_in[1], d_in[2], d_in[3], d_in[4], d_in[5], d_in[6], d_in[7],
          d_in[8], d_in[9], d_in[10], d_in[11], d_in[12], d_in[13], d_in[14], d_in[15],
          d_in[16], d_in[17], d_in[18], d_in[19], d_in[20], d_in[21], d_out,
          (char*)d_ws, 0, 0, 0ull, 0ull, 1, t0, (u64)WS_S2_OFF, (u64)WS_GU_OFF);
      cfgcn_fused<<<dim3(64), dim3(768), 0, stream>>>(
          d_in[0], d_in[1], d_in[2], d_in[3], d_in[4], d_in[5], d_in[6], d_in[7],
          d_in[8], d_in[9], d_in[10], d_in[11], d_in[12], d_in[13], d_in[14], d_in[15],
          d_in[16], d_in[17], d_in[18], d_in[19], d_in[20], d_in[21], d_out,
          (char*)d_ws, 1, t0, (u64)WS_S2_OFF, (u64)WS_GU_OFF, 0, 0, 0ull, 0ull);
    }
  } else {
    cfgcn<<<dim3(64), dim3(768), 0, stream>>>(
        d_in[0], d_in[1], d_in[2], d_in[3], d_in[4], d_in[5], d_in[6], d_in[7],
        d_in[8], d_in[9], d_in[10], d_in[11], d_in[12], d_in[13], d_in[14], d_in[15],
        d_in[16], d_in[17], d_in[18], d_in[19], d_in[20], d_in[21], d_out);
  }
}